// Round 2
// baseline (301.097 us; speedup 1.0000x reference)
//
#include <hip/hip_runtime.h>

// Problem: B=32,T=12,N=325,D=64,H=4,HD=16,M_SP=32,M_T=6, SCALE=0.25
// Inputs fp32 (+ int32 mode lists); output fp32.
//
// Key identities used:
//  * temporal branch: softmax axis == mean axis  =>  out = vf/6. Whole branch is
//    v=x@Wv_t^T (fake (n',t') reshape r = n'*12+t'), drop Nyquist of 12-pt rfft, /6.
//  * rfft over n commutes with channel linear => one DFT of x, then 64x64 matmuls.
//  * norms: ||q||^2 computed directly as sum q^2 fused into k_linear2's MFMA pass.
//  * GCN: Wc = W_mlp @ W_fc1 folded; out = A_rownorm @ (x @ Wc^T) + b.
//
// R9 (this round):
//  - ATOMIC TAIL FIX: k_linear2's 975x2 same-address device atomicAdds (cross-XCD
//    serialized RMW drain ~55us; signature: dur invariant R7->R8, avg occupancy
//    ~1/3 of peak) replaced by per-block partial writes to OFF_NPART; k_spatial3
//    reduces the 7.8KB of partials redundantly per block at startup. Memset gone.
//  - k_spatial3: 512 threads / 8 waves (phase A: 2 accA tiles/wave, phase B:
//    6 acc2 tiles/wave, softmax outer loop 8->4 iterations, wbar split into two
//    LDS halves to keep atomic contention constant). Doubles occupancy, halves
//    the per-thread serial VALU chain.

typedef unsigned short u16;
typedef short short8 __attribute__((ext_vector_type(8)));
typedef float floatx4 __attribute__((ext_vector_type(4)));

__device__ __forceinline__ u16 f2bf(float f) {
  union { float fp; unsigned int u; } v; v.fp = f;
  unsigned int x = v.u;
  x += 0x7FFF + ((x >> 16) & 1);   // RNE
  return (u16)(x >> 16);
}

// ---- workspace layout (float offsets; u16 arrays count as size/2 floats) ----
constexpr size_t OFF_NPART = 4096;      // 975*2  per-block [sum q^2, sum k^2]
constexpr size_t OFF_WQA  = 8208;       // 15872   |weights_Q|
constexpr size_t OFF_ANB  = 24080;      // u16[325*352]   row-norm adj, bf16, col-pad 352
constexpr size_t OFF_TB   = 81280;      // u16[64*352]    DFT matrix bf16, rows interleaved re/im
constexpr size_t OFF_T2   = 102080;     // u16[325*64]    irfft: [n][2j]=wc_j cos, [n][2j+1]=-wc_j sin
constexpr size_t OFF_OFT  = 112480;     // u16[384*64*64] spectrum [bt][d][2j|2j+1] (re,im)
constexpr size_t OFF_XCT  = 898912;     // u16[384*64*352] xc transposed [bt][d][n], n-pad 352
constexpr size_t OFF_VT   = 5224288;    // f32[124800*64]  x @ Wv_t^T
constexpr size_t OFF_ALT  = 13211488;   // f32[665600]     alternating sums
// bf16 weight tables alias ALT: written by k_prep, last read by k_spatial3,
// overwritten by k_alt (which runs after k_spatial3).
constexpr size_t OFF_WBB  = OFF_ALT;          // u16[256*64]  [Wc|Wvt|Wq|Wk]
constexpr size_t OFF_WSPB = OFF_ALT + 8192;   // u16[192*64]  [Wq|Wk|Wv]

// ===========  K2: WBB/WSPB, |wQ|, adj row-norm (bf16), twiddles, XCT pads  ===========
__global__ __launch_bounds__(256) void k_prep(const float* __restrict__ adj,
                                              const float* __restrict__ Wmlp,
                                              const float* __restrict__ Wfc1,
                                              const float* __restrict__ wQ,
                                              const float* __restrict__ Wvt,
                                              const float* __restrict__ Wq,
                                              const float* __restrict__ Wk,
                                              const float* __restrict__ Wv,
                                              const int* __restrict__ sp_modes,
                                              float* __restrict__ ws) {
  __shared__ float red[256];
  const int tid = threadIdx.x;
  const int blk = blockIdx.x;
  u16* WBBu = (u16*)(ws + OFF_WBB);
  if (blk == 0) {
    // Wc = Wmlp @ Wfc1, straight to bf16 rows 0..63 of WBB
    for (int o = tid; o < 4096; o += 256) {
      int g = o >> 6, dd = o & 63;
      float s = 0.f;
      for (int e = 0; e < 64; ++e)
        s = fmaf(Wmlp[g * 64 + e], Wfc1[e * 64 + dd], s);
      WBBu[o] = f2bf(s);
    }
  } else if (blk < 9) {
    for (int i = (blk - 1) * 256 + tid; i < 15872; i += 2048)
      ws[OFF_WQA + i] = fabsf(wQ[i]);
  } else if (blk < 334) {
    const int n = blk - 9;
    float p = 0.f;
    for (int k = tid; k < 325; k += 256) p += adj[n * 325 + k];
    red[tid] = p;
    __syncthreads();
    for (int s2 = 128; s2 > 0; s2 >>= 1) {
      if (tid < s2) red[tid] += red[tid + s2];
      __syncthreads();
    }
    const float inv = 1.f / red[0];
    u16* ANB = (u16*)(ws + OFF_ANB);
    for (int k = tid; k < 352; k += 256)
      ANB[(size_t)n * 352 + k] = (k < 325) ? f2bf(adj[n * 325 + k] * inv) : (u16)0;
  } else if (blk < 366) {
    const int j = blk - 334;  // < 32
    const int f = sp_modes[j];
    const float wgt = (f == 0) ? 1.f : 2.f;
    u16* T2B = (u16*)(ws + OFF_T2);
    u16* TB = (u16*)(ws + OFF_TB);
    // interleaved row order: rows 8g+0..3 = re f(4g..4g+3); 8g+4..7 = im
    const int row_re = 8 * (j >> 2) + (j & 3);
    const int row_im = row_re + 4;
    for (int n = tid; n < 352; n += 256) {
      float c = 0.f, s = 0.f;
      if (n < 325) {
        int mm = (f * n) % 325;               // exact range reduction
        float th = 6.283185307179586f * (float)mm * (1.f / 325.f);
        c = cosf(th);
        s = sinf(th);
      }
      TB[(size_t)row_re * 352 + n] = f2bf(c);
      TB[(size_t)row_im * 352 + n] = f2bf(-s);
      if (n < 325) {
        T2B[(size_t)n * 64 + 2 * j] = f2bf(wgt * (1.f / 325.f) * c);
        T2B[(size_t)n * 64 + 2 * j + 1] = f2bf(-wgt * (1.f / 325.f) * s);
      }
    }
  } else if (blk == 366) {
    // WBB rows 64..255: Wvt | Wq | Wk
    for (int i = tid; i < 12288; i += 256) {
      const int r = i >> 6, e = i & 63;
      const float* src = (r < 64) ? Wvt : (r < 128) ? Wq : Wk;
      WBBu[4096 + i] = f2bf(src[(size_t)(r & 63) * 64 + e]);
    }
  } else if (blk == 367) {
    u16* WSPBu = (u16*)(ws + OFF_WSPB);
    for (int i = tid; i < 12288; i += 256) {
      const int r = i >> 6, e = i & 63;
      const float* src = (r < 64) ? Wq : (r < 128) ? Wk : Wv;
      WSPBu[i] = f2bf(src[(size_t)(r & 63) * 64 + e]);
    }
  } else {
    // zero XCT n-pads [bt][d][325..352)
    const int idx = (blk - 368) * 256 + tid;   // < 24576 = 384*64
    u16* p = (u16*)(ws + OFF_XCT) + (size_t)(idx >> 6) * 22528 + (size_t)(idx & 63) * 352;
    for (int c = 325; c < 352; ++c) p[c] = 0;
  }
}

// =======  K4 (R9): one MFMA pass over x: xc->XCT, vt->VT, ||q||^2/||k||^2  =======
// 975 blocks x 128 rows x 512 threads (8 waves, 16 rows/wave, acc[16]).
// A = x[128][64] bf16 in LDS (stride 72). B = WBB (global bf16, fragment-ready).
// Norm partials: one float2 store per block (NO global atomics — see R9 note).
__global__ __launch_bounds__(512, 3) void k_linear2(const float* __restrict__ x,
                                                    float* __restrict__ ws) {
  __shared__ __align__(16) u16 XA[128 * 72];   // 18432 B; reused as xcT[64][132]
  __shared__ float reds[16];
  const int tid = threadIdx.x;
  const int wv = tid >> 6, lane = tid & 63, lc = lane & 15, quad = lane >> 4;
  const size_t base = (size_t)blockIdx.x * 128;
  const u16* WBBu = (const u16*)(ws + OFF_WBB);

  for (int i = tid; i < 2048; i += 512) {
    const int row = i >> 4, e0 = (i & 15) * 4;
    const float4 v = *(const float4*)(x + (base + row) * 64 + e0);
    u16* dst = &XA[row * 72 + e0];
    dst[0] = f2bf(v.x); dst[1] = f2bf(v.y); dst[2] = f2bf(v.z); dst[3] = f2bf(v.w);
  }
  __syncthreads();

  floatx4 acc[16] = {};
#pragma unroll
  for (int kc = 0; kc < 2; ++kc) {
    const short8 af = *(const short8*)&XA[(16 * wv + lc) * 72 + kc * 32 + quad * 8];
#pragma unroll
    for (int ni = 0; ni < 16; ++ni) {
      const short8 bf_ = *(const short8*)&WBBu[(ni * 16 + lc) * 64 + kc * 32 + quad * 8];
      acc[ni] = __builtin_amdgcn_mfma_f32_16x16x32_bf16(af, bf_, acc[ni], 0, 0, 0);
    }
  }

  // VT (f32) + q/k squared partial sums
  float sq = 0.f, sk = 0.f;
#pragma unroll
  for (int reg = 0; reg < 4; ++reg) {
    const int row = 16 * wv + quad * 4 + reg;
#pragma unroll
    for (int ni = 0; ni < 4; ++ni)
      ws[OFF_VT + (base + row) * 64 + ni * 16 + lc] = acc[4 + ni][reg];
#pragma unroll
    for (int ni = 0; ni < 4; ++ni) {
      const float v = acc[8 + ni][reg];
      sq = fmaf(v, v, sq);
    }
#pragma unroll
    for (int ni = 0; ni < 4; ++ni) {
      const float v = acc[12 + ni][reg];
      sk = fmaf(v, v, sk);
    }
  }
  for (int off = 32; off > 0; off >>= 1) {
    sq += __shfl_down(sq, off);
    sk += __shfl_down(sk, off);
  }
  if (lane == 0) { reds[wv] = sq; reds[8 + wv] = sk; }
  __syncthreads();   // also: all af reads of XA complete past this point
  if (tid == 0) {
    const float a = reds[0] + reds[1] + reds[2] + reds[3] +
                    reds[4] + reds[5] + reds[6] + reds[7];
    const float b = reds[8] + reds[9] + reds[10] + reds[11] +
                    reds[12] + reds[13] + reds[14] + reds[15];
    *(float2*)(ws + OFF_NPART + 2 * (size_t)blockIdx.x) = make_float2(a, b);
  }

  // xc -> xcT[64 d][132] bf16 reusing XA (stride 132: 66 dw = +2 banks/lane)
  u16* xcT = XA;
#pragma unroll
  for (int ni = 0; ni < 4; ++ni)
#pragma unroll
    for (int reg = 0; reg < 4; ++reg)
      xcT[(ni * 16 + lc) * 132 + 16 * wv + quad * 4 + reg] = f2bf(acc[ni][reg]);
  __syncthreads();
  u16* XCT = (u16*)(ws + OFF_XCT);
  for (int i = tid; i < 8192; i += 512) {
    const int d = i >> 7, r = i & 127;
    const unsigned int row = (unsigned int)(base + r);
    const unsigned int bt = row / 325u;
    const unsigned int n = row - bt * 325u;
    XCT[(size_t)bt * 22528 + (size_t)d * 352 + n] = xcT[d * 132 + r];
  }
}

// =======  K3 (R9): spatial branch per bt — 512 threads / 8 waves  =======
__global__ __launch_bounds__(512) void k_spatial3(const float* __restrict__ x,
                                                  float* __restrict__ ws) {
  __shared__ __align__(16) float smem[12544];   // 50,176 B
  const int tid = threadIdx.x;
  const int bt = blockIdx.x;
  const int lane = tid & 63, wv = tid >> 6;
  const int lc = lane & 15, quad = lane >> 4;
  const int wg = wv & 3;    // row-group wave (mode rows)
  const int wh = wv >> 2;   // tile-half selector

  // ---- norm partial reduce (7.8KB, redundant per block; replaces atomics) ----
  {
    float psq = 0.f, psk = 0.f;
    for (int p = tid; p < 975; p += 512) {
      const float2 v = *(const float2*)(ws + OFF_NPART + 2 * (size_t)p);
      psq += v.x; psk += v.y;
    }
    for (int off = 32; off > 0; off >>= 1) {
      psq += __shfl_down(psq, off);
      psk += __shfl_down(psk, off);
    }
    if (lane == 0) { smem[12480 + wv] = psq; smem[12488 + wv] = psk; }
  }

  // ---------------- Phase A: DFT GEMM (double-buffered x-tile) ----------------
  u16* Bt = (u16*)smem;                 // [2][64 e][40 k]  2 x 5120 B
  u16* xfl2 = (u16*)smem + 5120;        // [2 chunk][64 m][40]  5120 B
  const u16* TB = (const u16*)(ws + OFF_TB);
  const u16* WSPBu = (const u16*)(ws + OFF_WSPB);
  const float* xb = x + (size_t)bt * 20800;
  const int br = tid & 31, beg = (tid >> 5) * 4;

  auto stageB = [&](int kc, u16* dst) {
    const int k0 = kc * 32;
    float v[4];
    if (k0 + br < 325) {
      *(float4*)v = *(const float4*)(xb + (size_t)(k0 + br) * 64 + beg);
    } else {
#pragma unroll
      for (int u = 0; u < 4; ++u) v[u] = 0.f;
    }
#pragma unroll
    for (int u = 0; u < 4; ++u) dst[(beg + u) * 40 + br] = f2bf(v[u]);
  };

  floatx4 accA[2] = {};
  stageB(0, Bt);
  __syncthreads();   // covers norm-partial smem writes too
  for (int kc = 0; kc < 11; ++kc) {
    u16* cur = Bt + (kc & 1) * 2560;
    if (kc < 10) stageB(kc + 1, Bt + ((kc + 1) & 1) * 2560);
    const short8 af = *(const short8*)&TB[(size_t)(16 * wg + lc) * 352 + kc * 32 + quad * 8];
#pragma unroll
    for (int ti = 0; ti < 2; ++ti) {
      const int t = wh * 2 + ti;
      const short8 bf_ = *(const short8*)&cur[(t * 16 + lc) * 40 + quad * 8];
      accA[ti] = __builtin_amdgcn_mfma_f32_16x16x32_bf16(af, bf_, accA[ti], 0, 0, 0);
    }
    __syncthreads();
  }

  // xf staged CHUNKED by 32-e halves, stride-40 rows (no row aliasing)
#pragma unroll
  for (int ti = 0; ti < 2; ++ti) {
    const int t = wh * 2 + ti;
#pragma unroll
    for (int r = 0; r < 4; ++r)
      xfl2[wh * 2560 + (16 * wg + quad * 4 + r) * 40 + ti * 16 + lc] =
          f2bf(accA[ti][r]);
  }
  __syncthreads();

  // ---------------- Phase B: projection GEMM (W frags from global) ----------------
  floatx4 acc2[6] = {};
#pragma unroll
  for (int kc2 = 0; kc2 < 2; ++kc2) {
    const short8 af2 = *(const short8*)&xfl2[kc2 * 2560 + (16 * wg + lc) * 40 + quad * 8];
#pragma unroll
    for (int tt = 0; tt < 6; ++tt) {
      const int t = wh * 6 + tt;
      const short8 bf2 = *(const short8*)&WSPBu[(t * 16 + lc) * 64 + kc2 * 32 + quad * 8];
      acc2[tt] = __builtin_amdgcn_mfma_f32_16x16x32_bf16(af2, bf2, acc2[tt], 0, 0, 0);
    }
  }
  __syncthreads();

  // ---------------- Phase C ----------------
  float* sq_q = smem;             // [32][64]
  float* sq_k = smem + 2048;      // [32][64] -> absk*SCALE/||k||
  float* vfre = smem + 4096;
  float* vfim = smem + 6144;
  float* wbar = smem + 8192;      // two halves [2][32][64]
  for (int i = tid; i < 4096; i += 512) wbar[i] = 0.f;
  {
    const int fb = 8 * wg + ((quad >= 2) ? 4 : 0);
    const int isim = quad & 1;
#pragma unroll
    for (int tt = 0; tt < 6; ++tt) {
      const int t = wh * 6 + tt;
      const int mat = t >> 2;
      const int d = (t & 3) * 16 + lc;
#pragma unroll
      for (int r = 0; r < 4; ++r) {
        const float v = acc2[tt][r];
        if (mat == 2) {
          if (isim) vfim[(fb + r) * 64 + d] = v;
          else vfre[(fb + r) * 64 + d] = v;
        } else {
          const float s2 = v * v + __shfl_xor(v * v, 16);
          if (!isim) {
            if (mat == 0) sq_q[(fb + r) * 64 + d] = s2;
            else sq_k[(fb + r) * 64 + d] = s2;
          }
        }
      }
    }
  }
  __syncthreads();
  float nqs = 0.f, nks = 0.f;
#pragma unroll
  for (int w = 0; w < 8; ++w) { nqs += smem[12480 + w]; nks += smem[12488 + w]; }
  const float inv_nq = rsqrtf(nqs);
  const float inv_nk = rsqrtf(nks);
  for (int i = tid; i < 2048; i += 512)
    sq_k[i] = 0.25f * inv_nk * sqrtf(sq_k[i]);
  __syncthreads();
  {
    const int d = tid & 63, fb2 = (tid >> 6) & 7, hd = d & 15;
    float* wbarH = wbar + (tid >> 8) * 2048;
    const float* wqa = ws + OFF_WQA;
    float wacc[32];
#pragma unroll
    for (int j = 0; j < 32; ++j) wacc[j] = 0.f;
    for (int r4 = 0; r4 < 4; ++r4) {
      const int m = fb2 + (r4 << 3);
      const float aq = inv_nq * sqrtf(sq_q[m * 64 + d]);
      float sv[32];
      float mx = -1e30f;
#pragma unroll
      for (int j = 0; j < 32; ++j) {
        const float a = (j == 0) ? aq : wqa[(m * 31 + (j - 1)) * 16 + hd];
        const float s = sq_k[j * 64 + d] * a;
        sv[j] = s;
        mx = fmaxf(mx, s);
      }
      float sum = 0.f;
#pragma unroll
      for (int j = 0; j < 32; ++j) {
        const float ev = __expf(sv[j] - mx);
        sv[j] = ev;
        sum += ev;
      }
      const float sc = 0.03125f / sum;
#pragma unroll
      for (int j = 0; j < 32; ++j) wacc[j] += sv[j] * sc;
    }
#pragma unroll
    for (int j = 0; j < 32; ++j) atomicAdd(&wbarH[j * 64 + d], wacc[j]);
  }
  __syncthreads();
  // OFT[bt][d][2j|2j+1] packed bf16, coalesced uint writes
  unsigned int* OFTu = (unsigned int*)(ws + OFF_OFT) + (size_t)bt * 2048;
  for (int i2 = tid; i2 < 2048; i2 += 512) {
    const int d = i2 >> 5, j = i2 & 31;
    const float w = wbar[j * 64 + d] + wbar[2048 + j * 64 + d];
    const unsigned int lo = f2bf(vfre[j * 64 + d] * w);
    const unsigned int hi = f2bf(vfim[j * 64 + d] * w);
    OFTu[i2] = lo | (hi << 16);
  }
}

// =======  K5: alt[b,n',d] = sum_s (-1)^s vt[b, n'*12+s, d]  =======
__global__ __launch_bounds__(256) void k_alt(float* __restrict__ ws) {
  const int idx = blockIdx.x * 256 + threadIdx.x;
  if (idx >= 32 * 325 * 64) return;
  const int dd = idx & 63;
  const int n = (idx >> 6) % 325;
  const int b = idx / (64 * 325);
  const float* vt = ws + OFF_VT + ((size_t)b * 3900 + (size_t)n * 12) * 64 + dd;
  float s = 0.f, sign = 1.f;
  for (int k = 0; k < 12; ++k) {
    s += sign * vt[k * 64];
    sign = -sign;
  }
  ws[OFF_ALT + idx] = s;
}

// =======  K6: barrier-free MFMA — C = AN@XCT + T2@OFT, + temporal + bias  =======
// All operands bf16 fragment-ready in ws; no LDS, no __syncthreads in main loop.
__global__ __launch_bounds__(256) void k_final2(const float* __restrict__ bmlp,
                                                float* __restrict__ ws,
                                                float* __restrict__ out) {
  const int tid = threadIdx.x;
  const int bt = blockIdx.x / 3, mc = blockIdx.x % 3;
  const int m0 = mc * 128;
  const int wave = tid >> 6, lane = tid & 63;
  const int quad = lane >> 4, lc = lane & 15;

  const u16* ANB = (const u16*)(ws + OFF_ANB);
  const u16* T2B = (const u16*)(ws + OFF_T2);
  const u16* XCT = (const u16*)(ws + OFF_XCT) + (size_t)bt * 22528;
  const u16* OFT = (const u16*)(ws + OFF_OFT) + (size_t)bt * 4096;

  floatx4 acc[2][4] = {};

#pragma unroll
  for (int c13 = 0; c13 < 13; ++c13) {
    const bool gcn = (c13 < 11);
    const u16* Asrc = gcn ? ANB : T2B;
    const int astr = gcn ? 352 : 64;
    const int acol = gcn ? c13 * 32 : (c13 - 11) * 32;
    const u16* Bsrc = gcn ? XCT : OFT;
    const int bstr = gcn ? 352 : 64;
    short8 af[2], bf_[4];
#pragma unroll
    for (int mi = 0; mi < 2; ++mi) {
      const int gr = m0 + wave * 32 + mi * 16 + lc;
      short8 a = {};
      if (gr < 325)
        a = *(const short8*)&Asrc[(size_t)gr * astr + acol + quad * 8];
      af[mi] = a;
    }
#pragma unroll
    for (int ni = 0; ni < 4; ++ni)
      bf_[ni] = *(const short8*)&Bsrc[(size_t)(ni * 16 + lc) * bstr + acol + quad * 8];
#pragma unroll
    for (int mi = 0; mi < 2; ++mi)
#pragma unroll
      for (int ni = 0; ni < 4; ++ni)
        acc[mi][ni] = __builtin_amdgcn_mfma_f32_16x16x32_bf16(
            af[mi], bf_[ni], acc[mi][ni], 0, 0, 0);
  }

  const int b = bt / 12, t = bt - b * 12;
  const float sgn = (t & 1) ? -1.f : 1.f;
#pragma unroll
  for (int ni = 0; ni < 4; ++ni) {
    const int d = ni * 16 + lc;
    const float bias = bmlp[d];
#pragma unroll
    for (int mi = 0; mi < 2; ++mi) {
#pragma unroll
      for (int reg = 0; reg < 4; ++reg) {
        const int n = m0 + wave * 32 + mi * 16 + quad * 4 + reg;
        if (n >= 325) continue;
        const float v = ws[OFF_VT + ((size_t)b * 3900 + (size_t)n * 12 + t) * 64 + d];
        const float al = ws[OFF_ALT + ((size_t)b * 325 + n) * 64 + d];
        const float te = (v - sgn * al * (1.f / 12.f)) * (1.f / 6.f);
        out[((size_t)bt * 325 + n) * 64 + d] = acc[mi][ni][reg] + bias + te;
      }
    }
  }
}

extern "C" void kernel_launch(void* const* d_in, const int* in_sizes, int n_in,
                              void* d_out, int out_size, void* d_ws, size_t ws_size,
                              hipStream_t stream) {
  const float* x = (const float*)d_in[0];
  const float* adj = (const float*)d_in[1];
  const float* Wq_g = (const float*)d_in[2];
  const float* Wk_g = (const float*)d_in[3];
  const float* Wv_g = (const float*)d_in[4];
  // d_in[5], d_in[6] (Wq_t, Wk_t), d_in[12] (weights_Q_t), d_in[14] (t_modes):
  // dead code — temporal softmax axis == mean axis => out = vf/6.
  const float* Wv_t = (const float*)d_in[7];
  const float* Wfc1 = (const float*)d_in[8];
  const float* Wmlp = (const float*)d_in[9];
  const float* bmlp = (const float*)d_in[10];
  const float* wQ = (const float*)d_in[11];
  const int* sp_modes = (const int*)d_in[13];
  float* ws = (float*)d_ws;
  float* out = (float*)d_out;

  (void)in_sizes; (void)n_in; (void)out_size; (void)ws_size;

  k_prep<<<464, 256, 0, stream>>>(adj, Wmlp, Wfc1, wQ, Wv_t, Wq_g, Wk_g, Wv_g,
                                  sp_modes, ws);
  k_linear2<<<975, 512, 0, stream>>>(x, ws);
  k_spatial3<<<384, 512, 0, stream>>>(x, ws);
  k_alt<<<2600, 256, 0, stream>>>(ws);
  k_final2<<<1152, 256, 0, stream>>>(bmlp, ws, out);
}

// Round 3
// 255.231 us; speedup vs baseline: 1.1797x; 1.1797x over previous
//
#include <hip/hip_runtime.h>

// Problem: B=32,T=12,N=325,D=64,H=4,HD=16,M_SP=32,M_T=6, SCALE=0.25
// Inputs fp32 (+ int32 mode lists); output fp32.
//
// Key identities used:
//  * temporal branch: softmax axis == mean axis  =>  out = vf/6. Whole branch is
//    v=x@Wv_t^T (fake (n',t') reshape r = n'*12+t'), drop Nyquist of 12-pt rfft, /6.
//    R10: te = (vt - sgn*alt/12)/6 = ((x_s - sgn*xa_n/12)/6) @ Wvt^T  (linearity!)
//    where xa[b,n'] = sum_s (-1)^s x[b, n'*12+s]. VT (32MB) never materialized.
//  * rfft over n commutes with channel linear => one DFT of x, then 64x64 matmuls.
//  * norms: ||q||^2 computed directly as sum q^2 fused into k_linear2's MFMA pass.
//  * GCN: Wc = W_mlp @ W_fc1 folded; out = A_rownorm @ (x @ Wc^T) + b.
//
// R10 (this round):
//  - STORE-DRAIN THEORY: linear2's dur (~57us) tracked its 49MB store volume at a
//    flat ~1TB/s across 3 structurally different versions (occupancy signature:
//    waves resident but waiting on store retirement). Cut bytes, not structure.
//  - k_linear2: VT eliminated (B = [Wc|Wq|Wk], acc[12]). WRITE 49 -> 17.4 MB.
//  - k_alt -> k_xa: alternating sum over x rows directly (reads x, writes 2.7MB).
//  - k_final2: + fused te GEMM: A-frag = f2bf((x_row - sgn*xa/12)/6) vs prepped
//    bf16 Wvt (OFF_WVTB), accumulating into the same acc. No VT/ALT gather.
//  - k_spatial3: reverted to the R8 256-thread structure (proven <=56us); R9's
//    8-wave split halved per-wave ILP and doubled barrier rendezvous cost.
//    Norm inputs from OFF_NPART partials (reduced in a short prologue).

typedef unsigned short u16;
typedef short short8 __attribute__((ext_vector_type(8)));
typedef float floatx4 __attribute__((ext_vector_type(4)));

__device__ __forceinline__ u16 f2bf(float f) {
  union { float fp; unsigned int u; } v; v.fp = f;
  unsigned int x = v.u;
  x += 0x7FFF + ((x >> 16) & 1);   // RNE
  return (u16)(x >> 16);
}

// ---- workspace layout (float offsets; u16 arrays count as size/2 floats) ----
constexpr size_t OFF_NPART = 4096;      // 975*2  per-block [sum q^2, sum k^2]
constexpr size_t OFF_WQA  = 8208;       // 15872   |weights_Q|
constexpr size_t OFF_ANB  = 24080;      // u16[325*352]   row-norm adj, bf16, col-pad 352
constexpr size_t OFF_TB   = 81280;      // u16[64*352]    DFT matrix bf16, rows interleaved re/im
constexpr size_t OFF_WVTB = 92544;      // u16[64*64]     Wvt bf16 (for k_final2 te GEMM)
constexpr size_t OFF_WBB  = 94592;      // u16[192*64]    [Wc|Wq|Wk] bf16 (k_linear2 B)
constexpr size_t OFF_T2   = 102080;     // u16[325*64]    irfft: [n][2j]=wc_j cos, [n][2j+1]=-wc_j sin
constexpr size_t OFF_OFT  = 112480;     // u16[384*64*64] spectrum [bt][d][2j|2j+1] (re,im)
constexpr size_t OFF_XCT  = 898912;     // u16[384*64*352] xc transposed [bt][d][n], n-pad 352
constexpr size_t OFF_XA   = 13211488;   // f32[32*325*64]  alternating x sums (written by k_xa)
// WSPB aliases the XA region: written by k_prep, last read by k_spatial3,
// clobbered by k_xa (which runs after k_spatial3).
constexpr size_t OFF_WSPB = OFF_XA + 8192;   // u16[192*64]  [Wq|Wk|Wv]

// ===========  K2: weights bf16, |wQ|, adj row-norm, twiddles, XCT pads  ===========
__global__ __launch_bounds__(256) void k_prep(const float* __restrict__ adj,
                                              const float* __restrict__ Wmlp,
                                              const float* __restrict__ Wfc1,
                                              const float* __restrict__ wQ,
                                              const float* __restrict__ Wvt,
                                              const float* __restrict__ Wq,
                                              const float* __restrict__ Wk,
                                              const float* __restrict__ Wv,
                                              const int* __restrict__ sp_modes,
                                              float* __restrict__ ws) {
  __shared__ float red[256];
  const int tid = threadIdx.x;
  const int blk = blockIdx.x;
  u16* WBBu = (u16*)(ws + OFF_WBB);
  if (blk == 0) {
    // Wc = Wmlp @ Wfc1, straight to bf16 rows 0..63 of WBB
    for (int o = tid; o < 4096; o += 256) {
      int g = o >> 6, dd = o & 63;
      float s = 0.f;
      for (int e = 0; e < 64; ++e)
        s = fmaf(Wmlp[g * 64 + e], Wfc1[e * 64 + dd], s);
      WBBu[o] = f2bf(s);
    }
  } else if (blk < 9) {
    for (int i = (blk - 1) * 256 + tid; i < 15872; i += 2048)
      ws[OFF_WQA + i] = fabsf(wQ[i]);
  } else if (blk < 334) {
    const int n = blk - 9;
    float p = 0.f;
    for (int k = tid; k < 325; k += 256) p += adj[n * 325 + k];
    red[tid] = p;
    __syncthreads();
    for (int s2 = 128; s2 > 0; s2 >>= 1) {
      if (tid < s2) red[tid] += red[tid + s2];
      __syncthreads();
    }
    const float inv = 1.f / red[0];
    u16* ANB = (u16*)(ws + OFF_ANB);
    for (int k = tid; k < 352; k += 256)
      ANB[(size_t)n * 352 + k] = (k < 325) ? f2bf(adj[n * 325 + k] * inv) : (u16)0;
  } else if (blk < 366) {
    const int j = blk - 334;  // < 32
    const int f = sp_modes[j];
    const float wgt = (f == 0) ? 1.f : 2.f;
    u16* T2B = (u16*)(ws + OFF_T2);
    u16* TB = (u16*)(ws + OFF_TB);
    // interleaved row order: rows 8g+0..3 = re f(4g..4g+3); 8g+4..7 = im
    const int row_re = 8 * (j >> 2) + (j & 3);
    const int row_im = row_re + 4;
    for (int n = tid; n < 352; n += 256) {
      float c = 0.f, s = 0.f;
      if (n < 325) {
        int mm = (f * n) % 325;               // exact range reduction
        float th = 6.283185307179586f * (float)mm * (1.f / 325.f);
        c = cosf(th);
        s = sinf(th);
      }
      TB[(size_t)row_re * 352 + n] = f2bf(c);
      TB[(size_t)row_im * 352 + n] = f2bf(-s);
      if (n < 325) {
        T2B[(size_t)n * 64 + 2 * j] = f2bf(wgt * (1.f / 325.f) * c);
        T2B[(size_t)n * 64 + 2 * j + 1] = f2bf(-wgt * (1.f / 325.f) * s);
      }
    }
  } else if (blk == 366) {
    // WBB rows 64..191: Wq | Wk
    for (int i = tid; i < 8192; i += 256) {
      const int r = i >> 6, e = i & 63;
      const float* src = (r < 64) ? Wq : Wk;
      WBBu[4096 + i] = f2bf(src[(size_t)(r & 63) * 64 + e]);
    }
  } else if (blk == 367) {
    u16* WSPBu = (u16*)(ws + OFF_WSPB);
    for (int i = tid; i < 12288; i += 256) {
      const int r = i >> 6, e = i & 63;
      const float* src = (r < 64) ? Wq : (r < 128) ? Wk : Wv;
      WSPBu[i] = f2bf(src[(size_t)(r & 63) * 64 + e]);
    }
  } else if (blk == 368) {
    u16* WVTBu = (u16*)(ws + OFF_WVTB);
    for (int i = tid; i < 4096; i += 256) WVTBu[i] = f2bf(Wvt[i]);
  } else {
    // zero XCT n-pads [bt][d][325..352)
    const int idx = (blk - 369) * 256 + tid;   // < 24576 = 384*64
    u16* p = (u16*)(ws + OFF_XCT) + (size_t)(idx >> 6) * 22528 + (size_t)(idx & 63) * 352;
    for (int c = 325; c < 352; ++c) p[c] = 0;
  }
}

// =======  K4 (R10): MFMA pass over x: xc->XCT, ||q||^2/||k||^2 partials  =======
// 975 blocks x 128 rows x 512 threads (8 waves, 16 rows/wave, acc[12]).
// A = x[128][64] bf16 in LDS (stride 72). B = WBB (global bf16, fragment-ready).
__global__ __launch_bounds__(512, 3) void k_linear2(const float* __restrict__ x,
                                                    float* __restrict__ ws) {
  __shared__ __align__(16) u16 XA[128 * 72];   // 18432 B; reused as xcT[64][132]
  __shared__ float reds[16];
  const int tid = threadIdx.x;
  const int wv = tid >> 6, lane = tid & 63, lc = lane & 15, quad = lane >> 4;
  const size_t base = (size_t)blockIdx.x * 128;
  const u16* WBBu = (const u16*)(ws + OFF_WBB);

  for (int i = tid; i < 2048; i += 512) {
    const int row = i >> 4, e0 = (i & 15) * 4;
    const float4 v = *(const float4*)(x + (base + row) * 64 + e0);
    u16* dst = &XA[row * 72 + e0];
    dst[0] = f2bf(v.x); dst[1] = f2bf(v.y); dst[2] = f2bf(v.z); dst[3] = f2bf(v.w);
  }
  __syncthreads();

  floatx4 acc[12] = {};
#pragma unroll
  for (int kc = 0; kc < 2; ++kc) {
    const short8 af = *(const short8*)&XA[(16 * wv + lc) * 72 + kc * 32 + quad * 8];
#pragma unroll
    for (int ni = 0; ni < 12; ++ni) {
      const short8 bf_ = *(const short8*)&WBBu[(ni * 16 + lc) * 64 + kc * 32 + quad * 8];
      acc[ni] = __builtin_amdgcn_mfma_f32_16x16x32_bf16(af, bf_, acc[ni], 0, 0, 0);
    }
  }

  // q/k squared partial sums
  float sq = 0.f, sk = 0.f;
#pragma unroll
  for (int reg = 0; reg < 4; ++reg) {
#pragma unroll
    for (int ni = 0; ni < 4; ++ni) {
      const float v = acc[4 + ni][reg];
      sq = fmaf(v, v, sq);
    }
#pragma unroll
    for (int ni = 0; ni < 4; ++ni) {
      const float v = acc[8 + ni][reg];
      sk = fmaf(v, v, sk);
    }
  }
  for (int off = 32; off > 0; off >>= 1) {
    sq += __shfl_down(sq, off);
    sk += __shfl_down(sk, off);
  }
  if (lane == 0) { reds[wv] = sq; reds[8 + wv] = sk; }
  __syncthreads();   // also: all af reads of XA complete past this point
  if (tid == 0) {
    const float a = reds[0] + reds[1] + reds[2] + reds[3] +
                    reds[4] + reds[5] + reds[6] + reds[7];
    const float b = reds[8] + reds[9] + reds[10] + reds[11] +
                    reds[12] + reds[13] + reds[14] + reds[15];
    *(float2*)(ws + OFF_NPART + 2 * (size_t)blockIdx.x) = make_float2(a, b);
  }

  // xc -> xcT[64 d][132] bf16 reusing XA (stride 132: 66 dw = +2 banks/lane)
  u16* xcT = XA;
#pragma unroll
  for (int ni = 0; ni < 4; ++ni)
#pragma unroll
    for (int reg = 0; reg < 4; ++reg)
      xcT[(ni * 16 + lc) * 132 + 16 * wv + quad * 4 + reg] = f2bf(acc[ni][reg]);
  __syncthreads();
  u16* XCT = (u16*)(ws + OFF_XCT);
  for (int i = tid; i < 8192; i += 512) {
    const int d = i >> 7, r = i & 127;
    const unsigned int row = (unsigned int)(base + r);
    const unsigned int bt = row / 325u;
    const unsigned int n = row - bt * 325u;
    XCT[(size_t)bt * 22528 + (size_t)d * 352 + n] = xcT[d * 132 + r];
  }
}

// =======  K3 (R10): spatial branch per bt — R8 256-thread structure  =======
__global__ __launch_bounds__(256) void k_spatial3(const float* __restrict__ x,
                                                  float* __restrict__ ws) {
  __shared__ __align__(16) float smem[10256];   // 41,024 B
  const int tid = threadIdx.x;
  const int bt = blockIdx.x;
  const int lane = tid & 63, wv = tid >> 6;
  const int lc = lane & 15, quad = lane >> 4;

  // ---- norm partial reduce (redundant per block; replaces global atomics) ----
  {
    float psq = 0.f, psk = 0.f;
    for (int p = tid; p < 975; p += 256) {
      const float2 v = *(const float2*)(ws + OFF_NPART + 2 * (size_t)p);
      psq += v.x; psk += v.y;
    }
    for (int off = 32; off > 0; off >>= 1) {
      psq += __shfl_down(psq, off);
      psk += __shfl_down(psk, off);
    }
    if (lane == 0) { smem[10240 + wv] = psq; smem[10248 + wv] = psk; }
  }

  // ---------------- Phase A: DFT GEMM (double-buffered x-tile) ----------------
  u16* Bt = (u16*)smem;                 // [2][64 e][40 k]  2 x 5120 B
  u16* xfl2 = (u16*)smem + 5120;        // [2 chunk][64 m][40]  5120 B
  const u16* TB = (const u16*)(ws + OFF_TB);
  const u16* WSPBu = (const u16*)(ws + OFF_WSPB);
  const float* xb = x + (size_t)bt * 20800;
  const int br = tid & 31, be0 = (tid >> 5) * 8;

  auto stageB = [&](int kc, u16* dst) {
    const int k0 = kc * 32;
    float v[8];
    if (k0 + br < 325) {
      const float* src = xb + (size_t)(k0 + br) * 64 + be0;
      *(float4*)v = *(const float4*)src;
      *(float4*)(v + 4) = *(const float4*)(src + 4);
    } else {
#pragma unroll
      for (int u = 0; u < 8; ++u) v[u] = 0.f;
    }
#pragma unroll
    for (int u = 0; u < 8; ++u) dst[(be0 + u) * 40 + br] = f2bf(v[u]);
  };

  floatx4 accA[4] = {};
  stageB(0, Bt);
  __syncthreads();   // covers norm-partial smem writes too
  for (int kc = 0; kc < 11; ++kc) {
    u16* cur = Bt + (kc & 1) * 2560;
    if (kc < 10) stageB(kc + 1, Bt + ((kc + 1) & 1) * 2560);
    const short8 af = *(const short8*)&TB[(size_t)(16 * wv + lc) * 352 + kc * 32 + quad * 8];
#pragma unroll
    for (int t = 0; t < 4; ++t) {
      const short8 bf_ = *(const short8*)&cur[(t * 16 + lc) * 40 + quad * 8];
      accA[t] = __builtin_amdgcn_mfma_f32_16x16x32_bf16(af, bf_, accA[t], 0, 0, 0);
    }
    __syncthreads();
  }

  // xf staged CHUNKED by 32-e halves, stride-40 rows (no row aliasing)
#pragma unroll
  for (int t = 0; t < 4; ++t)
#pragma unroll
    for (int r = 0; r < 4; ++r)
      xfl2[(t >> 1) * 2560 + (16 * wv + quad * 4 + r) * 40 + (t & 1) * 16 + lc] =
          f2bf(accA[t][r]);
  __syncthreads();

  // ---------------- Phase B: projection GEMM (W frags from global) ----------------
  floatx4 acc2[12] = {};
#pragma unroll
  for (int kc2 = 0; kc2 < 2; ++kc2) {
    const short8 af2 = *(const short8*)&xfl2[kc2 * 2560 + (16 * wv + lc) * 40 + quad * 8];
#pragma unroll
    for (int t = 0; t < 12; ++t) {
      const short8 bf2 = *(const short8*)&WSPBu[(t * 16 + lc) * 64 + kc2 * 32 + quad * 8];
      acc2[t] = __builtin_amdgcn_mfma_f32_16x16x32_bf16(af2, bf2, acc2[t], 0, 0, 0);
    }
  }
  __syncthreads();

  // ---------------- Phase C ----------------
  float* sq_q = smem;             // [32][64]
  float* sq_k = smem + 2048;      // [32][64] -> absk*SCALE/||k||
  float* vfre = smem + 4096;
  float* vfim = smem + 6144;
  float* wbar = smem + 8192;
  for (int i = tid; i < 2048; i += 256) wbar[i] = 0.f;
  {
    const int fb = 8 * wv + ((quad >= 2) ? 4 : 0);
    const int isim = quad & 1;
#pragma unroll
    for (int t = 0; t < 12; ++t) {
      const int mat = t >> 2;
      const int d = (t & 3) * 16 + lc;
#pragma unroll
      for (int r = 0; r < 4; ++r) {
        const float v = acc2[t][r];
        if (mat == 2) {
          if (isim) vfim[(fb + r) * 64 + d] = v;
          else vfre[(fb + r) * 64 + d] = v;
        } else {
          const float s2 = v * v + __shfl_xor(v * v, 16);
          if (!isim) {
            if (mat == 0) sq_q[(fb + r) * 64 + d] = s2;
            else sq_k[(fb + r) * 64 + d] = s2;
          }
        }
      }
    }
  }
  __syncthreads();
  float nqs = 0.f, nks = 0.f;
#pragma unroll
  for (int w = 0; w < 4; ++w) { nqs += smem[10240 + w]; nks += smem[10248 + w]; }
  const float inv_nq = rsqrtf(nqs);
  const float inv_nk = rsqrtf(nks);
  for (int i = tid; i < 2048; i += 256)
    sq_k[i] = 0.25f * inv_nk * sqrtf(sq_k[i]);
  __syncthreads();
  {
    const int d = tid & 63, fb2 = tid >> 6, hd = d & 15;
    const float* wqa = ws + OFF_WQA;
    float wacc[32];
#pragma unroll
    for (int j = 0; j < 32; ++j) wacc[j] = 0.f;
    for (int r8 = 0; r8 < 8; ++r8) {
      const int m = fb2 + (r8 << 2);
      const float aq = inv_nq * sqrtf(sq_q[m * 64 + d]);
      float sv[32];
      float mx = -1e30f;
#pragma unroll
      for (int j = 0; j < 32; ++j) {
        const float a = (j == 0) ? aq : wqa[(m * 31 + (j - 1)) * 16 + hd];
        const float s = sq_k[j * 64 + d] * a;
        sv[j] = s;
        mx = fmaxf(mx, s);
      }
      float sum = 0.f;
#pragma unroll
      for (int j = 0; j < 32; ++j) {
        const float ev = __expf(sv[j] - mx);
        sv[j] = ev;
        sum += ev;
      }
      const float sc = 0.03125f / sum;
#pragma unroll
      for (int j = 0; j < 32; ++j) wacc[j] += sv[j] * sc;
    }
#pragma unroll
    for (int j = 0; j < 32; ++j) atomicAdd(&wbar[j * 64 + d], wacc[j]);
  }
  __syncthreads();
  // OFT[bt][d][2j|2j+1] packed bf16, coalesced uint writes
  unsigned int* OFTu = (unsigned int*)(ws + OFF_OFT) + (size_t)bt * 2048;
  for (int i2 = tid; i2 < 2048; i2 += 256) {
    const int d = i2 >> 5, j = i2 & 31;
    const float w = wbar[j * 64 + d];
    const unsigned int lo = f2bf(vfre[j * 64 + d] * w);
    const unsigned int hi = f2bf(vfim[j * 64 + d] * w);
    OFTu[i2] = lo | (hi << 16);
  }
}

// =======  K5 (R10): xa[b,n',0:64] = sum_s (-1)^s x[b, n'*12+s, :]  =======
__global__ __launch_bounds__(256) void k_xa(const float* __restrict__ x,
                                            float* __restrict__ ws) {
  const int idx = blockIdx.x * 256 + threadIdx.x;
  if (idx >= 32 * 325 * 16) return;
  const int dq = idx & 15;            // float4 slot
  const int n = (idx >> 4) % 325;
  const int b = idx / (16 * 325);
  const float* xp = x + ((size_t)b * 3900 + (size_t)n * 12) * 64 + dq * 4;
  float4 s = make_float4(0.f, 0.f, 0.f, 0.f);
  float sign = 1.f;
  for (int k = 0; k < 12; ++k) {
    const float4 v = *(const float4*)(xp + (size_t)k * 64);
    s.x += sign * v.x; s.y += sign * v.y; s.z += sign * v.z; s.w += sign * v.w;
    sign = -sign;
  }
  *(float4*)(ws + OFF_XA + ((size_t)b * 325 + n) * 64 + dq * 4) = s;
}

// =======  K6 (R10): barrier-free MFMA — C = AN@XCT + T2@OFT + TE@Wvt + bias  =======
// All B-operands bf16 fragment-ready in ws; te A-frag built in-register from x,xa.
__global__ __launch_bounds__(256) void k_final2(const float* __restrict__ x,
                                                const float* __restrict__ bmlp,
                                                float* __restrict__ ws,
                                                float* __restrict__ out) {
  const int tid = threadIdx.x;
  const int bt = blockIdx.x / 3, mc = blockIdx.x % 3;
  const int m0 = mc * 128;
  const int wave = tid >> 6, lane = tid & 63;
  const int quad = lane >> 4, lc = lane & 15;

  const u16* ANB = (const u16*)(ws + OFF_ANB);
  const u16* T2B = (const u16*)(ws + OFF_T2);
  const u16* XCT = (const u16*)(ws + OFF_XCT) + (size_t)bt * 22528;
  const u16* OFT = (const u16*)(ws + OFF_OFT) + (size_t)bt * 4096;
  const u16* WVTBu = (const u16*)(ws + OFF_WVTB);

  const int b = bt / 12, t = bt - b * 12;
  const float sgn12 = ((t & 1) ? -1.f : 1.f) * (1.f / 12.f);

  floatx4 acc[2][4] = {};

#pragma unroll
  for (int c13 = 0; c13 < 13; ++c13) {
    const bool gcn = (c13 < 11);
    const u16* Asrc = gcn ? ANB : T2B;
    const int astr = gcn ? 352 : 64;
    const int acol = gcn ? c13 * 32 : (c13 - 11) * 32;
    const u16* Bsrc = gcn ? XCT : OFT;
    const int bstr = gcn ? 352 : 64;
    short8 af[2], bf_[4];
#pragma unroll
    for (int mi = 0; mi < 2; ++mi) {
      const int gr = m0 + wave * 32 + mi * 16 + lc;
      short8 a = {};
      if (gr < 325)
        a = *(const short8*)&Asrc[(size_t)gr * astr + acol + quad * 8];
      af[mi] = a;
    }
#pragma unroll
    for (int ni = 0; ni < 4; ++ni)
      bf_[ni] = *(const short8*)&Bsrc[(size_t)(ni * 16 + lc) * bstr + acol + quad * 8];
#pragma unroll
    for (int mi = 0; mi < 2; ++mi)
#pragma unroll
      for (int ni = 0; ni < 4; ++ni)
        acc[mi][ni] = __builtin_amdgcn_mfma_f32_16x16x32_bf16(
            af[mi], bf_[ni], acc[mi][ni], 0, 0, 0);
  }

  // --- te GEMM: A' = (x_row(n*12+t) - sgn*xa_n/12)/6, B = Wvt ---
#pragma unroll
  for (int kc = 0; kc < 2; ++kc) {
    const int k0 = kc * 32 + quad * 8;
    short8 af[2];
#pragma unroll
    for (int mi = 0; mi < 2; ++mi) {
      const int nr = m0 + wave * 32 + mi * 16 + lc;
      short8 a = {};
      if (nr < 325) {
        const float* xp = x + ((size_t)b * 3900 + (size_t)nr * 12 + t) * 64 + k0;
        const float* xap = ws + OFF_XA + ((size_t)b * 325 + nr) * 64 + k0;
        float xv[8], av[8];
        *(float4*)xv = *(const float4*)xp;
        *(float4*)(xv + 4) = *(const float4*)(xp + 4);
        *(float4*)av = *(const float4*)xap;
        *(float4*)(av + 4) = *(const float4*)(xap + 4);
#pragma unroll
        for (int u = 0; u < 8; ++u)
          a[u] = (short)f2bf((xv[u] - sgn12 * av[u]) * (1.f / 6.f));
      }
      af[mi] = a;
    }
#pragma unroll
    for (int ni = 0; ni < 4; ++ni) {
      const short8 bf_ = *(const short8*)&WVTBu[(size_t)(ni * 16 + lc) * 64 + k0];
#pragma unroll
      for (int mi = 0; mi < 2; ++mi)
        acc[mi][ni] = __builtin_amdgcn_mfma_f32_16x16x32_bf16(
            af[mi], bf_, acc[mi][ni], 0, 0, 0);
    }
  }

#pragma unroll
  for (int ni = 0; ni < 4; ++ni) {
    const int d = ni * 16 + lc;
    const float bias = bmlp[d];
#pragma unroll
    for (int mi = 0; mi < 2; ++mi) {
#pragma unroll
      for (int reg = 0; reg < 4; ++reg) {
        const int n = m0 + wave * 32 + mi * 16 + quad * 4 + reg;
        if (n >= 325) continue;
        out[((size_t)bt * 325 + n) * 64 + d] = acc[mi][ni][reg] + bias;
      }
    }
  }
}

extern "C" void kernel_launch(void* const* d_in, const int* in_sizes, int n_in,
                              void* d_out, int out_size, void* d_ws, size_t ws_size,
                              hipStream_t stream) {
  const float* x = (const float*)d_in[0];
  const float* adj = (const float*)d_in[1];
  const float* Wq_g = (const float*)d_in[2];
  const float* Wk_g = (const float*)d_in[3];
  const float* Wv_g = (const float*)d_in[4];
  // d_in[5], d_in[6] (Wq_t, Wk_t), d_in[12] (weights_Q_t), d_in[14] (t_modes):
  // dead code — temporal softmax axis == mean axis => out = vf/6.
  const float* Wv_t = (const float*)d_in[7];
  const float* Wfc1 = (const float*)d_in[8];
  const float* Wmlp = (const float*)d_in[9];
  const float* bmlp = (const float*)d_in[10];
  const float* wQ = (const float*)d_in[11];
  const int* sp_modes = (const int*)d_in[13];
  float* ws = (float*)d_ws;
  float* out = (float*)d_out;

  (void)in_sizes; (void)n_in; (void)out_size; (void)ws_size;

  k_prep<<<465, 256, 0, stream>>>(adj, Wmlp, Wfc1, wQ, Wv_t, Wq_g, Wk_g, Wv_g,
                                  sp_modes, ws);
  k_linear2<<<975, 512, 0, stream>>>(x, ws);
  k_spatial3<<<384, 256, 0, stream>>>(x, ws);
  k_xa<<<650, 256, 0, stream>>>(x, ws);
  k_final2<<<1152, 256, 0, stream>>>(x, bmlp, ws, out);
}

// Round 4
// 253.905 us; speedup vs baseline: 1.1859x; 1.0052x over previous
//
#include <hip/hip_runtime.h>

// Problem: B=32,T=12,N=325,D=64,H=4,HD=16,M_SP=32,M_T=6, SCALE=0.25
// Inputs fp32 (+ int32 mode lists); output fp32.
//
// Key identities used:
//  * temporal branch: softmax axis == mean axis  =>  out = vf/6. Whole branch is
//    v=x@Wv_t^T (fake (n',t') reshape r = n'*12+t'), drop Nyquist of 12-pt rfft, /6.
//    R10: te = (vt - sgn*alt/12)/6 = ((x_s - sgn*xa_n/12)/6) @ Wvt^T  (linearity!)
//    where xa[b,n'] = sum_s (-1)^s x[b, n'*12+s]. VT (32MB) never materialized.
//  * rfft over n commutes with channel linear => one DFT of x, then 64x64 matmuls.
//  * norms: ||q||^2 computed directly as sum q^2 fused into k_linear2's MFMA pass.
//  * GCN: Wc = W_mlp @ W_fc1 folded; out = A_rownorm @ (x @ Wc^T) + b.
//
// R11 (this round): k_spatial3 de-latency-fication.
//  - Old phase A: 11 double-buffered chunks, each {2 gl loads, f2bf, ds_write,
//    barrier, 4 MFMA, barrier} — compute per chunk ~0, so the block serially eats
//    ~11 memory round-trips + 22 barriers (~26us/block, 384 blocks = 1.5 rounds).
//  - New phase A: stage the WHOLE 325x64 x-tile to LDS up front (3 grouped load
//    batches -> 3 round trips), ONE barrier, then 44 MFMAs barrier-free with
//    B-frags from the staged tile (stride 360 u16) and A-frags from global TB.
//  - LDS re-laid out: XB[64][360] (46KB) -> dead after phase A; xfl2 reuses its
//    first 10.2KB; phase-C float arrays at byte 10,240..51,200. 51.3KB = 3 blk/CU.

typedef unsigned short u16;
typedef short short8 __attribute__((ext_vector_type(8)));
typedef float floatx4 __attribute__((ext_vector_type(4)));

__device__ __forceinline__ u16 f2bf(float f) {
  union { float fp; unsigned int u; } v; v.fp = f;
  unsigned int x = v.u;
  x += 0x7FFF + ((x >> 16) & 1);   // RNE
  return (u16)(x >> 16);
}

// ---- workspace layout (float offsets; u16 arrays count as size/2 floats) ----
constexpr size_t OFF_NPART = 4096;      // 975*2  per-block [sum q^2, sum k^2]
constexpr size_t OFF_WQA  = 8208;       // 15872   |weights_Q|
constexpr size_t OFF_ANB  = 24080;      // u16[325*352]   row-norm adj, bf16, col-pad 352
constexpr size_t OFF_TB   = 81280;      // u16[64*352]    DFT matrix bf16, rows interleaved re/im
constexpr size_t OFF_WVTB = 92544;      // u16[64*64]     Wvt bf16 (for k_final2 te GEMM)
constexpr size_t OFF_WBB  = 94592;      // u16[192*64]    [Wc|Wq|Wk] bf16 (k_linear2 B)
constexpr size_t OFF_T2   = 102080;     // u16[325*64]    irfft: [n][2j]=wc_j cos, [n][2j+1]=-wc_j sin
constexpr size_t OFF_OFT  = 112480;     // u16[384*64*64] spectrum [bt][d][2j|2j+1] (re,im)
constexpr size_t OFF_XCT  = 898912;     // u16[384*64*352] xc transposed [bt][d][n], n-pad 352
constexpr size_t OFF_XA   = 13211488;   // f32[32*325*64]  alternating x sums (written by k_xa)
// WSPB aliases the XA region: written by k_prep, last read by k_spatial3,
// clobbered by k_xa (which runs after k_spatial3).
constexpr size_t OFF_WSPB = OFF_XA + 8192;   // u16[192*64]  [Wq|Wk|Wv]

// ===========  K2: weights bf16, |wQ|, adj row-norm, twiddles, XCT pads  ===========
__global__ __launch_bounds__(256) void k_prep(const float* __restrict__ adj,
                                              const float* __restrict__ Wmlp,
                                              const float* __restrict__ Wfc1,
                                              const float* __restrict__ wQ,
                                              const float* __restrict__ Wvt,
                                              const float* __restrict__ Wq,
                                              const float* __restrict__ Wk,
                                              const float* __restrict__ Wv,
                                              const int* __restrict__ sp_modes,
                                              float* __restrict__ ws) {
  __shared__ float red[256];
  const int tid = threadIdx.x;
  const int blk = blockIdx.x;
  u16* WBBu = (u16*)(ws + OFF_WBB);
  if (blk == 0) {
    // Wc = Wmlp @ Wfc1, straight to bf16 rows 0..63 of WBB
    for (int o = tid; o < 4096; o += 256) {
      int g = o >> 6, dd = o & 63;
      float s = 0.f;
      for (int e = 0; e < 64; ++e)
        s = fmaf(Wmlp[g * 64 + e], Wfc1[e * 64 + dd], s);
      WBBu[o] = f2bf(s);
    }
  } else if (blk < 9) {
    for (int i = (blk - 1) * 256 + tid; i < 15872; i += 2048)
      ws[OFF_WQA + i] = fabsf(wQ[i]);
  } else if (blk < 334) {
    const int n = blk - 9;
    float p = 0.f;
    for (int k = tid; k < 325; k += 256) p += adj[n * 325 + k];
    red[tid] = p;
    __syncthreads();
    for (int s2 = 128; s2 > 0; s2 >>= 1) {
      if (tid < s2) red[tid] += red[tid + s2];
      __syncthreads();
    }
    const float inv = 1.f / red[0];
    u16* ANB = (u16*)(ws + OFF_ANB);
    for (int k = tid; k < 352; k += 256)
      ANB[(size_t)n * 352 + k] = (k < 325) ? f2bf(adj[n * 325 + k] * inv) : (u16)0;
  } else if (blk < 366) {
    const int j = blk - 334;  // < 32
    const int f = sp_modes[j];
    const float wgt = (f == 0) ? 1.f : 2.f;
    u16* T2B = (u16*)(ws + OFF_T2);
    u16* TB = (u16*)(ws + OFF_TB);
    // interleaved row order: rows 8g+0..3 = re f(4g..4g+3); 8g+4..7 = im
    const int row_re = 8 * (j >> 2) + (j & 3);
    const int row_im = row_re + 4;
    for (int n = tid; n < 352; n += 256) {
      float c = 0.f, s = 0.f;
      if (n < 325) {
        int mm = (f * n) % 325;               // exact range reduction
        float th = 6.283185307179586f * (float)mm * (1.f / 325.f);
        c = cosf(th);
        s = sinf(th);
      }
      TB[(size_t)row_re * 352 + n] = f2bf(c);
      TB[(size_t)row_im * 352 + n] = f2bf(-s);
      if (n < 325) {
        T2B[(size_t)n * 64 + 2 * j] = f2bf(wgt * (1.f / 325.f) * c);
        T2B[(size_t)n * 64 + 2 * j + 1] = f2bf(-wgt * (1.f / 325.f) * s);
      }
    }
  } else if (blk == 366) {
    // WBB rows 64..191: Wq | Wk
    for (int i = tid; i < 8192; i += 256) {
      const int r = i >> 6, e = i & 63;
      const float* src = (r < 64) ? Wq : Wk;
      WBBu[4096 + i] = f2bf(src[(size_t)(r & 63) * 64 + e]);
    }
  } else if (blk == 367) {
    u16* WSPBu = (u16*)(ws + OFF_WSPB);
    for (int i = tid; i < 12288; i += 256) {
      const int r = i >> 6, e = i & 63;
      const float* src = (r < 64) ? Wq : (r < 128) ? Wk : Wv;
      WSPBu[i] = f2bf(src[(size_t)(r & 63) * 64 + e]);
    }
  } else if (blk == 368) {
    u16* WVTBu = (u16*)(ws + OFF_WVTB);
    for (int i = tid; i < 4096; i += 256) WVTBu[i] = f2bf(Wvt[i]);
  } else {
    // zero XCT n-pads [bt][d][325..352)
    const int idx = (blk - 369) * 256 + tid;   // < 24576 = 384*64
    u16* p = (u16*)(ws + OFF_XCT) + (size_t)(idx >> 6) * 22528 + (size_t)(idx & 63) * 352;
    for (int c = 325; c < 352; ++c) p[c] = 0;
  }
}

// =======  K4: MFMA pass over x: xc->XCT, ||q||^2/||k||^2 partials  =======
// 975 blocks x 128 rows x 512 threads (8 waves, 16 rows/wave, acc[12]).
// A = x[128][64] bf16 in LDS (stride 72). B = WBB (global bf16, fragment-ready).
__global__ __launch_bounds__(512, 3) void k_linear2(const float* __restrict__ x,
                                                    float* __restrict__ ws) {
  __shared__ __align__(16) u16 XA[128 * 72];   // 18432 B; reused as xcT[64][132]
  __shared__ float reds[16];
  const int tid = threadIdx.x;
  const int wv = tid >> 6, lane = tid & 63, lc = lane & 15, quad = lane >> 4;
  const size_t base = (size_t)blockIdx.x * 128;
  const u16* WBBu = (const u16*)(ws + OFF_WBB);

  for (int i = tid; i < 2048; i += 512) {
    const int row = i >> 4, e0 = (i & 15) * 4;
    const float4 v = *(const float4*)(x + (base + row) * 64 + e0);
    u16* dst = &XA[row * 72 + e0];
    dst[0] = f2bf(v.x); dst[1] = f2bf(v.y); dst[2] = f2bf(v.z); dst[3] = f2bf(v.w);
  }
  __syncthreads();

  floatx4 acc[12] = {};
#pragma unroll
  for (int kc = 0; kc < 2; ++kc) {
    const short8 af = *(const short8*)&XA[(16 * wv + lc) * 72 + kc * 32 + quad * 8];
#pragma unroll
    for (int ni = 0; ni < 12; ++ni) {
      const short8 bf_ = *(const short8*)&WBBu[(ni * 16 + lc) * 64 + kc * 32 + quad * 8];
      acc[ni] = __builtin_amdgcn_mfma_f32_16x16x32_bf16(af, bf_, acc[ni], 0, 0, 0);
    }
  }

  // q/k squared partial sums
  float sq = 0.f, sk = 0.f;
#pragma unroll
  for (int reg = 0; reg < 4; ++reg) {
#pragma unroll
    for (int ni = 0; ni < 4; ++ni) {
      const float v = acc[4 + ni][reg];
      sq = fmaf(v, v, sq);
    }
#pragma unroll
    for (int ni = 0; ni < 4; ++ni) {
      const float v = acc[8 + ni][reg];
      sk = fmaf(v, v, sk);
    }
  }
  for (int off = 32; off > 0; off >>= 1) {
    sq += __shfl_down(sq, off);
    sk += __shfl_down(sk, off);
  }
  if (lane == 0) { reds[wv] = sq; reds[8 + wv] = sk; }
  __syncthreads();   // also: all af reads of XA complete past this point
  if (tid == 0) {
    const float a = reds[0] + reds[1] + reds[2] + reds[3] +
                    reds[4] + reds[5] + reds[6] + reds[7];
    const float b = reds[8] + reds[9] + reds[10] + reds[11] +
                    reds[12] + reds[13] + reds[14] + reds[15];
    *(float2*)(ws + OFF_NPART + 2 * (size_t)blockIdx.x) = make_float2(a, b);
  }

  // xc -> xcT[64 d][132] bf16 reusing XA (stride 132: 66 dw = +2 banks/lane)
  u16* xcT = XA;
#pragma unroll
  for (int ni = 0; ni < 4; ++ni)
#pragma unroll
    for (int reg = 0; reg < 4; ++reg)
      xcT[(ni * 16 + lc) * 132 + 16 * wv + quad * 4 + reg] = f2bf(acc[ni][reg]);
  __syncthreads();
  u16* XCT = (u16*)(ws + OFF_XCT);
  for (int i = tid; i < 8192; i += 512) {
    const int d = i >> 7, r = i & 127;
    const unsigned int row = (unsigned int)(base + r);
    const unsigned int bt = row / 325u;
    const unsigned int n = row - bt * 325u;
    XCT[(size_t)bt * 22528 + (size_t)d * 352 + n] = xcT[d * 132 + r];
  }
}

// =======  K3 (R11): spatial branch per bt — whole-tile stage, barrier-free GEMMs  =======
// LDS: XB[64 e][360 n] u16 (46,080B) -> after phase A, bytes 0..10,240 reused as
// xfl2; phase-C float arrays at float idx 2560..12800; nred at 12800. 51,264B.
__global__ __launch_bounds__(256) void k_spatial3(const float* __restrict__ x,
                                                  float* __restrict__ ws) {
  __shared__ __align__(16) float smem[12816];
  const int tid = threadIdx.x;
  const int bt = blockIdx.x;
  const int lane = tid & 63, wv = tid >> 6;
  const int lc = lane & 15, quad = lane >> 4;
  u16* XBu = (u16*)smem;                       // [64 e][360 n]

  // ---- norm partial reduce (redundant per block; replaces global atomics) ----
  {
    float psq = 0.f, psk = 0.f;
    for (int p = tid; p < 975; p += 256) {
      const float2 v = *(const float2*)(ws + OFF_NPART + 2 * (size_t)p);
      psq += v.x; psk += v.y;
    }
    for (int off = 32; off > 0; off >>= 1) {
      psq += __shfl_down(psq, off);
      psk += __shfl_down(psk, off);
    }
    if (lane == 0) { smem[12800 + wv] = psq; smem[12808 + wv] = psk; }
  }

  // ---------------- stage whole x-tile -> XB (bf16, [e][n]) ----------------
  const u16* TB = (const u16*)(ws + OFF_TB);
  const u16* WSPBu = (const u16*)(ws + OFF_WSPB);
  const float* xb = x + (size_t)bt * 20800;
  const int br = tid & 31, be0 = (tid >> 5) * 8;

  {
    float va[4][8];
#pragma unroll
    for (int g = 0; g < 3; ++g) {
      const int nkc = (g < 2) ? 4 : 3;
#pragma unroll
      for (int u = 0; u < 4; ++u) {
        if (u >= nkc) break;
        const int k0 = (g * 4 + u) * 32;
        if (k0 + br < 325) {
          const float* src = xb + (size_t)(k0 + br) * 64 + be0;
          *(float4*)&va[u][0] = *(const float4*)src;
          *(float4*)&va[u][4] = *(const float4*)(src + 4);
        } else {
#pragma unroll
          for (int w = 0; w < 8; ++w) va[u][w] = 0.f;
        }
      }
#pragma unroll
      for (int u = 0; u < 4; ++u) {
        if (u >= nkc) break;
        const int k0 = (g * 4 + u) * 32;
#pragma unroll
        for (int w = 0; w < 8; ++w)
          XBu[(be0 + w) * 360 + k0 + br] = f2bf(va[u][w]);
      }
    }
  }
  __syncthreads();

  // ---------------- Phase A: DFT GEMM, barrier-free ----------------
  floatx4 accA[4] = {};
#pragma unroll
  for (int kc = 0; kc < 11; ++kc) {
    const short8 af = *(const short8*)&TB[(size_t)(16 * wv + lc) * 352 + kc * 32 + quad * 8];
#pragma unroll
    for (int t = 0; t < 4; ++t) {
      const short8 bf_ = *(const short8*)&XBu[(t * 16 + lc) * 360 + kc * 32 + quad * 8];
      accA[t] = __builtin_amdgcn_mfma_f32_16x16x32_bf16(af, bf_, accA[t], 0, 0, 0);
    }
  }
  __syncthreads();   // all XB reads done; bytes 0..10,240 now reused as xfl2

  // xf staged CHUNKED by 32-e halves, stride-40 rows (no row aliasing)
  u16* xfl2 = XBu;
#pragma unroll
  for (int t = 0; t < 4; ++t)
#pragma unroll
    for (int r = 0; r < 4; ++r)
      xfl2[(t >> 1) * 2560 + (16 * wv + quad * 4 + r) * 40 + (t & 1) * 16 + lc] =
          f2bf(accA[t][r]);
  __syncthreads();

  // ---------------- Phase B: projection GEMM (W frags from global) ----------------
  floatx4 acc2[12] = {};
#pragma unroll
  for (int kc2 = 0; kc2 < 2; ++kc2) {
    const short8 af2 = *(const short8*)&xfl2[kc2 * 2560 + (16 * wv + lc) * 40 + quad * 8];
#pragma unroll
    for (int t = 0; t < 12; ++t) {
      const short8 bf2 = *(const short8*)&WSPBu[(t * 16 + lc) * 64 + kc2 * 32 + quad * 8];
      acc2[t] = __builtin_amdgcn_mfma_f32_16x16x32_bf16(af2, bf2, acc2[t], 0, 0, 0);
    }
  }
  __syncthreads();

  // ---------------- Phase C ----------------
  float* sq_q = smem + 2560;      // [32][64]
  float* sq_k = smem + 4608;      // [32][64] -> absk*SCALE/||k||
  float* vfre = smem + 6656;
  float* vfim = smem + 8704;
  float* wbar = smem + 10752;
  for (int i = tid; i < 2048; i += 256) wbar[i] = 0.f;
  {
    const int fb = 8 * wv + ((quad >= 2) ? 4 : 0);
    const int isim = quad & 1;
#pragma unroll
    for (int t = 0; t < 12; ++t) {
      const int mat = t >> 2;
      const int d = (t & 3) * 16 + lc;
#pragma unroll
      for (int r = 0; r < 4; ++r) {
        const float v = acc2[t][r];
        if (mat == 2) {
          if (isim) vfim[(fb + r) * 64 + d] = v;
          else vfre[(fb + r) * 64 + d] = v;
        } else {
          const float s2 = v * v + __shfl_xor(v * v, 16);
          if (!isim) {
            if (mat == 0) sq_q[(fb + r) * 64 + d] = s2;
            else sq_k[(fb + r) * 64 + d] = s2;
          }
        }
      }
    }
  }
  __syncthreads();
  float nqs = 0.f, nks = 0.f;
#pragma unroll
  for (int w = 0; w < 4; ++w) { nqs += smem[12800 + w]; nks += smem[12808 + w]; }
  const float inv_nq = rsqrtf(nqs);
  const float inv_nk = rsqrtf(nks);
  for (int i = tid; i < 2048; i += 256)
    sq_k[i] = 0.25f * inv_nk * sqrtf(sq_k[i]);
  __syncthreads();
  {
    const int d = tid & 63, fb2 = tid >> 6, hd = d & 15;
    const float* wqa = ws + OFF_WQA;
    float wacc[32];
#pragma unroll
    for (int j = 0; j < 32; ++j) wacc[j] = 0.f;
    for (int r8 = 0; r8 < 8; ++r8) {
      const int m = fb2 + (r8 << 2);
      const float aq = inv_nq * sqrtf(sq_q[m * 64 + d]);
      float sv[32];
      float mx = -1e30f;
#pragma unroll
      for (int j = 0; j < 32; ++j) {
        const float a = (j == 0) ? aq : wqa[(m * 31 + (j - 1)) * 16 + hd];
        const float s = sq_k[j * 64 + d] * a;
        sv[j] = s;
        mx = fmaxf(mx, s);
      }
      float sum = 0.f;
#pragma unroll
      for (int j = 0; j < 32; ++j) {
        const float ev = __expf(sv[j] - mx);
        sv[j] = ev;
        sum += ev;
      }
      const float sc = 0.03125f / sum;
#pragma unroll
      for (int j = 0; j < 32; ++j) wacc[j] += sv[j] * sc;
    }
#pragma unroll
    for (int j = 0; j < 32; ++j) atomicAdd(&wbar[j * 64 + d], wacc[j]);
  }
  __syncthreads();
  // OFT[bt][d][2j|2j+1] packed bf16, coalesced uint writes
  unsigned int* OFTu = (unsigned int*)(ws + OFF_OFT) + (size_t)bt * 2048;
  for (int i2 = tid; i2 < 2048; i2 += 256) {
    const int d = i2 >> 5, j = i2 & 31;
    const float w = wbar[j * 64 + d];
    const unsigned int lo = f2bf(vfre[j * 64 + d] * w);
    const unsigned int hi = f2bf(vfim[j * 64 + d] * w);
    OFTu[i2] = lo | (hi << 16);
  }
}

// =======  K5: xa[b,n',0:64] = sum_s (-1)^s x[b, n'*12+s, :]  =======
__global__ __launch_bounds__(256) void k_xa(const float* __restrict__ x,
                                            float* __restrict__ ws) {
  const int idx = blockIdx.x * 256 + threadIdx.x;
  if (idx >= 32 * 325 * 16) return;
  const int dq = idx & 15;            // float4 slot
  const int n = (idx >> 4) % 325;
  const int b = idx / (16 * 325);
  const float* xp = x + ((size_t)b * 3900 + (size_t)n * 12) * 64 + dq * 4;
  float4 s = make_float4(0.f, 0.f, 0.f, 0.f);
  float sign = 1.f;
  for (int k = 0; k < 12; ++k) {
    const float4 v = *(const float4*)(xp + (size_t)k * 64);
    s.x += sign * v.x; s.y += sign * v.y; s.z += sign * v.z; s.w += sign * v.w;
    sign = -sign;
  }
  *(float4*)(ws + OFF_XA + ((size_t)b * 325 + n) * 64 + dq * 4) = s;
}

// =======  K6: barrier-free MFMA — C = AN@XCT + T2@OFT + TE@Wvt + bias  =======
// All B-operands bf16 fragment-ready in ws; te A-frag built in-register from x,xa.
__global__ __launch_bounds__(256) void k_final2(const float* __restrict__ x,
                                                const float* __restrict__ bmlp,
                                                float* __restrict__ ws,
                                                float* __restrict__ out) {
  const int tid = threadIdx.x;
  const int bt = blockIdx.x / 3, mc = blockIdx.x % 3;
  const int m0 = mc * 128;
  const int wave = tid >> 6, lane = tid & 63;
  const int quad = lane >> 4, lc = lane & 15;

  const u16* ANB = (const u16*)(ws + OFF_ANB);
  const u16* T2B = (const u16*)(ws + OFF_T2);
  const u16* XCT = (const u16*)(ws + OFF_XCT) + (size_t)bt * 22528;
  const u16* OFT = (const u16*)(ws + OFF_OFT) + (size_t)bt * 4096;
  const u16* WVTBu = (const u16*)(ws + OFF_WVTB);

  const int b = bt / 12, t = bt - b * 12;
  const float sgn12 = ((t & 1) ? -1.f : 1.f) * (1.f / 12.f);

  floatx4 acc[2][4] = {};

#pragma unroll
  for (int c13 = 0; c13 < 13; ++c13) {
    const bool gcn = (c13 < 11);
    const u16* Asrc = gcn ? ANB : T2B;
    const int astr = gcn ? 352 : 64;
    const int acol = gcn ? c13 * 32 : (c13 - 11) * 32;
    const u16* Bsrc = gcn ? XCT : OFT;
    const int bstr = gcn ? 352 : 64;
    short8 af[2], bf_[4];
#pragma unroll
    for (int mi = 0; mi < 2; ++mi) {
      const int gr = m0 + wave * 32 + mi * 16 + lc;
      short8 a = {};
      if (gr < 325)
        a = *(const short8*)&Asrc[(size_t)gr * astr + acol + quad * 8];
      af[mi] = a;
    }
#pragma unroll
    for (int ni = 0; ni < 4; ++ni)
      bf_[ni] = *(const short8*)&Bsrc[(size_t)(ni * 16 + lc) * bstr + acol + quad * 8];
#pragma unroll
    for (int mi = 0; mi < 2; ++mi)
#pragma unroll
      for (int ni = 0; ni < 4; ++ni)
        acc[mi][ni] = __builtin_amdgcn_mfma_f32_16x16x32_bf16(
            af[mi], bf_[ni], acc[mi][ni], 0, 0, 0);
  }

  // --- te GEMM: A' = (x_row(n*12+t) - sgn*xa_n/12)/6, B = Wvt ---
#pragma unroll
  for (int kc = 0; kc < 2; ++kc) {
    const int k0 = kc * 32 + quad * 8;
    short8 af[2];
#pragma unroll
    for (int mi = 0; mi < 2; ++mi) {
      const int nr = m0 + wave * 32 + mi * 16 + lc;
      short8 a = {};
      if (nr < 325) {
        const float* xp = x + ((size_t)b * 3900 + (size_t)nr * 12 + t) * 64 + k0;
        const float* xap = ws + OFF_XA + ((size_t)b * 325 + nr) * 64 + k0;
        float xv[8], av[8];
        *(float4*)xv = *(const float4*)xp;
        *(float4*)(xv + 4) = *(const float4*)(xp + 4);
        *(float4*)av = *(const float4*)xap;
        *(float4*)(av + 4) = *(const float4*)(xap + 4);
#pragma unroll
        for (int u = 0; u < 8; ++u)
          a[u] = (short)f2bf((xv[u] - sgn12 * av[u]) * (1.f / 6.f));
      }
      af[mi] = a;
    }
#pragma unroll
    for (int ni = 0; ni < 4; ++ni) {
      const short8 bf_ = *(const short8*)&WVTBu[(size_t)(ni * 16 + lc) * 64 + k0];
#pragma unroll
      for (int mi = 0; mi < 2; ++mi)
        acc[mi][ni] = __builtin_amdgcn_mfma_f32_16x16x32_bf16(
            af[mi], bf_, acc[mi][ni], 0, 0, 0);
    }
  }

#pragma unroll
  for (int ni = 0; ni < 4; ++ni) {
    const int d = ni * 16 + lc;
    const float bias = bmlp[d];
#pragma unroll
    for (int mi = 0; mi < 2; ++mi) {
#pragma unroll
      for (int reg = 0; reg < 4; ++reg) {
        const int n = m0 + wave * 32 + mi * 16 + quad * 4 + reg;
        if (n >= 325) continue;
        out[((size_t)bt * 325 + n) * 64 + d] = acc[mi][ni][reg] + bias;
      }
    }
  }
}

extern "C" void kernel_launch(void* const* d_in, const int* in_sizes, int n_in,
                              void* d_out, int out_size, void* d_ws, size_t ws_size,
                              hipStream_t stream) {
  const float* x = (const float*)d_in[0];
  const float* adj = (const float*)d_in[1];
  const float* Wq_g = (const float*)d_in[2];
  const float* Wk_g = (const float*)d_in[3];
  const float* Wv_g = (const float*)d_in[4];
  // d_in[5], d_in[6] (Wq_t, Wk_t), d_in[12] (weights_Q_t), d_in[14] (t_modes):
  // dead code — temporal softmax axis == mean axis => out = vf/6.
  const float* Wv_t = (const float*)d_in[7];
  const float* Wfc1 = (const float*)d_in[8];
  const float* Wmlp = (const float*)d_in[9];
  const float* bmlp = (const float*)d_in[10];
  const float* wQ = (const float*)d_in[11];
  const int* sp_modes = (const int*)d_in[13];
  float* ws = (float*)d_ws;
  float* out = (float*)d_out;

  (void)in_sizes; (void)n_in; (void)out_size; (void)ws_size;

  k_prep<<<465, 256, 0, stream>>>(adj, Wmlp, Wfc1, wQ, Wv_t, Wq_g, Wk_g, Wv_g,
                                  sp_modes, ws);
  k_linear2<<<975, 512, 0, stream>>>(x, ws);
  k_spatial3<<<384, 256, 0, stream>>>(x, ws);
  k_xa<<<650, 256, 0, stream>>>(x, ws);
  k_final2<<<1152, 256, 0, stream>>>(x, bmlp, ws, out);
}

// Round 5
// 233.725 us; speedup vs baseline: 1.2883x; 1.0863x over previous
//
#include <hip/hip_runtime.h>

// Problem: B=32,T=12,N=325,D=64,H=4,HD=16,M_SP=32,M_T=6, SCALE=0.25
// Inputs fp32 (+ int32 mode lists); output fp32.
//
// Key identities used:
//  * temporal branch: softmax axis == mean axis  =>  out = vf/6. Whole branch is
//    v=x@Wv_t^T (fake (n',t') reshape r = n'*12+t'), drop Nyquist of 12-pt rfft, /6.
//    te = (vt - sgn*alt/12)/6 = ((x_s - sgn*xa_n/12)/6) @ Wvt^T  (linearity);
//    xa[b,n'] = sum_s (-1)^s x[b, n'*12+s]. VT (32MB) never materialized.
//  * rfft over n commutes with channel linear => one DFT of x, then 64x64 matmuls.
//  * GCN: Wc = W_mlp @ W_fc1 folded; out = A_rownorm @ (x @ Wc^T) + b.
//
// R12 (this round): LAUNCH-LEVEL OVERLAP.
//  - R11 null result: spatial3 dur bit-identical (52.16us) under full internal
//    restructure => 384x4-wave blocks are latency-bound; nothing inside helps.
//    linear2 likewise ~45us block latency (store-retire). The fix is overlap:
//  - Norm partials (||q||^2,||k||^2) moved into k_prep as 975 extra MFMA blocks
//    (only cross-kernel dependency spatial3 had on linear2).
//  - k_mega = spatial3(384) + linear2(975, Wc-only, 256t) + xa(650) in ONE
//    launch: disjoint outputs (OFT/XCT/XA), no intra-launch dependencies.
//    spatial's latency hides under linear2's bandwidth work.
//  - Weight tables WBB/WSPB/WVTB relocated to the freed VT region (the old
//    WSPB<->XA aliasing would race now that xa runs concurrently with spatial).
//  - 3 launches total: prep+norm -> mega -> final2.

typedef unsigned short u16;
typedef short short8 __attribute__((ext_vector_type(8)));
typedef float floatx4 __attribute__((ext_vector_type(4)));

__device__ __forceinline__ u16 f2bf(float f) {
  union { float fp; unsigned int u; } v; v.fp = f;
  unsigned int x = v.u;
  x += 0x7FFF + ((x >> 16) & 1);   // RNE
  return (u16)(x >> 16);
}

// ---- workspace layout (float offsets; u16 arrays count as size/2 floats) ----
constexpr size_t OFF_NPART = 4096;      // 975*2  per-block [sum q^2, sum k^2]
constexpr size_t OFF_WQA  = 8208;       // 15872   |weights_Q|
constexpr size_t OFF_ANB  = 24080;      // u16[325*352]   row-norm adj, bf16, col-pad 352
constexpr size_t OFF_TB   = 81280;      // u16[64*352]    DFT matrix bf16, rows interleaved re/im
constexpr size_t OFF_T2   = 102080;     // u16[325*64]    irfft: [n][2j]=wc_j cos, [n][2j+1]=-wc_j sin
constexpr size_t OFF_OFT  = 112480;     // u16[384*64*64] spectrum [bt][d][2j|2j+1] (re,im)
constexpr size_t OFF_XCT  = 898912;     // u16[384*64*352] xc transposed [bt][d][n], n-pad 352
// weight tables live in the freed VT region (no aliasing with XA!)
constexpr size_t OFF_WBB  = 5224288;    // u16[64*64]   Wc bf16 (k_mega/linear2 B)
constexpr size_t OFF_WSPB = 5226336;    // u16[192*64]  [Wq|Wk|Wv] bf16 (spatial B)
constexpr size_t OFF_WVTB = 5232480;    // u16[64*64]   Wvt bf16 (k_final2 te GEMM)
constexpr size_t OFF_XA   = 13211488;   // f32[32*325*64]  alternating x sums

// ===========  K1: weights bf16, |wQ|, adj, twiddles, XCT pads, NORM partials  ===========
__global__ __launch_bounds__(256) void k_prep(const float* __restrict__ x,
                                              const float* __restrict__ adj,
                                              const float* __restrict__ Wmlp,
                                              const float* __restrict__ Wfc1,
                                              const float* __restrict__ wQ,
                                              const float* __restrict__ Wvt,
                                              const float* __restrict__ Wq,
                                              const float* __restrict__ Wk,
                                              const float* __restrict__ Wv,
                                              const int* __restrict__ sp_modes,
                                              float* __restrict__ ws) {
  __shared__ float red[256];
  __shared__ __align__(16) u16 XA[128 * 72];   // norm blocks only
  const int tid = threadIdx.x;
  const int blk = blockIdx.x;
  u16* WBBu = (u16*)(ws + OFF_WBB);
  if (blk >= 464) {
    // ---- norm partial blocks: ||q||^2, ||k||^2 over 128 rows of x ----
    const int blk2 = blk - 464;              // < 975
    const int wv = tid >> 6, lane = tid & 63, lc = lane & 15, quad = lane >> 4;
    const size_t base = (size_t)blk2 * 128;
    for (int i = tid; i < 2048; i += 256) {
      const int row = i >> 4, e0 = (i & 15) * 4;
      const float4 v = *(const float4*)(x + (base + row) * 64 + e0);
      u16* dst = &XA[row * 72 + e0];
      dst[0] = f2bf(v.x); dst[1] = f2bf(v.y); dst[2] = f2bf(v.z); dst[3] = f2bf(v.w);
    }
    __syncthreads();
    floatx4 acc[2][8] = {};
#pragma unroll
    for (int kc = 0; kc < 2; ++kc) {
      short8 af[2];
#pragma unroll
      for (int mi = 0; mi < 2; ++mi)
        af[mi] = *(const short8*)&XA[(32 * wv + 16 * mi + lc) * 72 + kc * 32 + quad * 8];
#pragma unroll
      for (int ni = 0; ni < 8; ++ni) {
        const int g = (ni & 3) * 16 + lc;
        const float* src = ((ni < 4) ? Wq : Wk) + (size_t)g * 64 + kc * 32 + quad * 8;
        float v8[8];
        *(float4*)v8 = *(const float4*)src;
        *(float4*)(v8 + 4) = *(const float4*)(src + 4);
        short8 bf_;
#pragma unroll
        for (int u = 0; u < 8; ++u) bf_[u] = (short)f2bf(v8[u]);
#pragma unroll
        for (int mi = 0; mi < 2; ++mi)
          acc[mi][ni] = __builtin_amdgcn_mfma_f32_16x16x32_bf16(af[mi], bf_, acc[mi][ni], 0, 0, 0);
      }
    }
    float sq = 0.f, sk = 0.f;
#pragma unroll
    for (int mi = 0; mi < 2; ++mi)
#pragma unroll
      for (int reg = 0; reg < 4; ++reg) {
#pragma unroll
        for (int ni = 0; ni < 4; ++ni) {
          const float v = acc[mi][ni][reg];
          sq = fmaf(v, v, sq);
        }
#pragma unroll
        for (int ni = 4; ni < 8; ++ni) {
          const float v = acc[mi][ni][reg];
          sk = fmaf(v, v, sk);
        }
      }
    for (int off = 32; off > 0; off >>= 1) {
      sq += __shfl_down(sq, off);
      sk += __shfl_down(sk, off);
    }
    if (lane == 0) { red[wv] = sq; red[8 + wv] = sk; }
    __syncthreads();
    if (tid == 0) {
      const float a = red[0] + red[1] + red[2] + red[3];
      const float b = red[8] + red[9] + red[10] + red[11];
      *(float2*)(ws + OFF_NPART + 2 * (size_t)blk2) = make_float2(a, b);
    }
    return;
  }
  if (blk == 0) {
    // Wc = Wmlp @ Wfc1, straight to bf16 (all linear2 needs)
    for (int o = tid; o < 4096; o += 256) {
      int g = o >> 6, dd = o & 63;
      float s = 0.f;
      for (int e = 0; e < 64; ++e)
        s = fmaf(Wmlp[g * 64 + e], Wfc1[e * 64 + dd], s);
      WBBu[o] = f2bf(s);
    }
  } else if (blk < 9) {
    for (int i = (blk - 1) * 256 + tid; i < 15872; i += 2048)
      ws[OFF_WQA + i] = fabsf(wQ[i]);
  } else if (blk < 334) {
    const int n = blk - 9;
    float p = 0.f;
    for (int k = tid; k < 325; k += 256) p += adj[n * 325 + k];
    red[tid] = p;
    __syncthreads();
    for (int s2 = 128; s2 > 0; s2 >>= 1) {
      if (tid < s2) red[tid] += red[tid + s2];
      __syncthreads();
    }
    const float inv = 1.f / red[0];
    u16* ANB = (u16*)(ws + OFF_ANB);
    for (int k = tid; k < 352; k += 256)
      ANB[(size_t)n * 352 + k] = (k < 325) ? f2bf(adj[n * 325 + k] * inv) : (u16)0;
  } else if (blk < 366) {
    const int j = blk - 334;  // < 32
    const int f = sp_modes[j];
    const float wgt = (f == 0) ? 1.f : 2.f;
    u16* T2B = (u16*)(ws + OFF_T2);
    u16* TB = (u16*)(ws + OFF_TB);
    // interleaved row order: rows 8g+0..3 = re f(4g..4g+3); 8g+4..7 = im
    const int row_re = 8 * (j >> 2) + (j & 3);
    const int row_im = row_re + 4;
    for (int n = tid; n < 352; n += 256) {
      float c = 0.f, s = 0.f;
      if (n < 325) {
        int mm = (f * n) % 325;               // exact range reduction
        float th = 6.283185307179586f * (float)mm * (1.f / 325.f);
        c = cosf(th);
        s = sinf(th);
      }
      TB[(size_t)row_re * 352 + n] = f2bf(c);
      TB[(size_t)row_im * 352 + n] = f2bf(-s);
      if (n < 325) {
        T2B[(size_t)n * 64 + 2 * j] = f2bf(wgt * (1.f / 325.f) * c);
        T2B[(size_t)n * 64 + 2 * j + 1] = f2bf(-wgt * (1.f / 325.f) * s);
      }
    }
  } else if (blk == 366) {
    u16* WSPBu = (u16*)(ws + OFF_WSPB);
    for (int i = tid; i < 12288; i += 256) {
      const int r = i >> 6, e = i & 63;
      const float* src = (r < 64) ? Wq : (r < 128) ? Wk : Wv;
      WSPBu[i] = f2bf(src[(size_t)(r & 63) * 64 + e]);
    }
  } else if (blk == 367) {
    u16* WVTBu = (u16*)(ws + OFF_WVTB);
    for (int i = tid; i < 4096; i += 256) WVTBu[i] = f2bf(Wvt[i]);
  } else {
    // zero XCT n-pads [bt][d][325..352)   (blk 368..463 -> 96 blocks)
    const int idx = (blk - 368) * 256 + tid;   // < 24576 = 384*64
    u16* p = (u16*)(ws + OFF_XCT) + (size_t)(idx >> 6) * 22528 + (size_t)(idx & 63) * 352;
    for (int c = 325; c < 352; ++c) p[c] = 0;
  }
}

// ===========  K2 (R12): MEGA — spatial(384) | linear2(975) | xa(650)  ===========
// Disjoint outputs: OFT / XCT / XA. No intra-launch dependencies.
__global__ __launch_bounds__(256) void k_mega(const float* __restrict__ x,
                                              float* __restrict__ ws) {
  __shared__ __align__(16) float smem[12816];   // 51,264 B (spatial worst case)
  const int tid = threadIdx.x;
  const int blk = blockIdx.x;
  const int lane = tid & 63, wv = tid >> 6;
  const int lc = lane & 15, quad = lane >> 4;

  if (blk < 384) {
    // ================= spatial branch per bt (R11 structure) =================
    const int bt = blk;
    u16* XBu = (u16*)smem;                       // [64 e][360 n]

    // ---- norm partial reduce (from k_prep's 975 partials) ----
    {
      float psq = 0.f, psk = 0.f;
      for (int p = tid; p < 975; p += 256) {
        const float2 v = *(const float2*)(ws + OFF_NPART + 2 * (size_t)p);
        psq += v.x; psk += v.y;
      }
      for (int off = 32; off > 0; off >>= 1) {
        psq += __shfl_down(psq, off);
        psk += __shfl_down(psk, off);
      }
      if (lane == 0) { smem[12800 + wv] = psq; smem[12808 + wv] = psk; }
    }

    const u16* TB = (const u16*)(ws + OFF_TB);
    const u16* WSPBu = (const u16*)(ws + OFF_WSPB);
    const float* xb = x + (size_t)bt * 20800;
    const int br = tid & 31, be0 = (tid >> 5) * 8;

    // ---- stage whole x-tile -> XB (bf16, [e][n]) ----
    {
      float va[4][8];
#pragma unroll
      for (int g = 0; g < 3; ++g) {
        const int nkc = (g < 2) ? 4 : 3;
#pragma unroll
        for (int u = 0; u < 4; ++u) {
          if (u >= nkc) break;
          const int k0 = (g * 4 + u) * 32;
          if (k0 + br < 325) {
            const float* src = xb + (size_t)(k0 + br) * 64 + be0;
            *(float4*)&va[u][0] = *(const float4*)src;
            *(float4*)&va[u][4] = *(const float4*)(src + 4);
          } else {
#pragma unroll
            for (int w = 0; w < 8; ++w) va[u][w] = 0.f;
          }
        }
#pragma unroll
        for (int u = 0; u < 4; ++u) {
          if (u >= nkc) break;
          const int k0 = (g * 4 + u) * 32;
#pragma unroll
          for (int w = 0; w < 8; ++w)
            XBu[(be0 + w) * 360 + k0 + br] = f2bf(va[u][w]);
        }
      }
    }
    __syncthreads();

    // ---- Phase A: DFT GEMM, barrier-free ----
    floatx4 accA[4] = {};
#pragma unroll
    for (int kc = 0; kc < 11; ++kc) {
      const short8 af = *(const short8*)&TB[(size_t)(16 * wv + lc) * 352 + kc * 32 + quad * 8];
#pragma unroll
      for (int t = 0; t < 4; ++t) {
        const short8 bf_ = *(const short8*)&XBu[(t * 16 + lc) * 360 + kc * 32 + quad * 8];
        accA[t] = __builtin_amdgcn_mfma_f32_16x16x32_bf16(af, bf_, accA[t], 0, 0, 0);
      }
    }
    __syncthreads();   // all XB reads done; first 10,240B reused as xfl2

    u16* xfl2 = XBu;
#pragma unroll
    for (int t = 0; t < 4; ++t)
#pragma unroll
      for (int r = 0; r < 4; ++r)
        xfl2[(t >> 1) * 2560 + (16 * wv + quad * 4 + r) * 40 + (t & 1) * 16 + lc] =
            f2bf(accA[t][r]);
    __syncthreads();

    // ---- Phase B: projection GEMM ----
    floatx4 acc2[12] = {};
#pragma unroll
    for (int kc2 = 0; kc2 < 2; ++kc2) {
      const short8 af2 = *(const short8*)&xfl2[kc2 * 2560 + (16 * wv + lc) * 40 + quad * 8];
#pragma unroll
      for (int t = 0; t < 12; ++t) {
        const short8 bf2 = *(const short8*)&WSPBu[(t * 16 + lc) * 64 + kc2 * 32 + quad * 8];
        acc2[t] = __builtin_amdgcn_mfma_f32_16x16x32_bf16(af2, bf2, acc2[t], 0, 0, 0);
      }
    }
    __syncthreads();

    // ---- Phase C ----
    float* sq_q = smem + 2560;      // [32][64]
    float* sq_k = smem + 4608;      // [32][64] -> absk*SCALE/||k||
    float* vfre = smem + 6656;
    float* vfim = smem + 8704;
    float* wbar = smem + 10752;
    for (int i = tid; i < 2048; i += 256) wbar[i] = 0.f;
    {
      const int fb = 8 * wv + ((quad >= 2) ? 4 : 0);
      const int isim = quad & 1;
#pragma unroll
      for (int t = 0; t < 12; ++t) {
        const int mat = t >> 2;
        const int d = (t & 3) * 16 + lc;
#pragma unroll
        for (int r = 0; r < 4; ++r) {
          const float v = acc2[t][r];
          if (mat == 2) {
            if (isim) vfim[(fb + r) * 64 + d] = v;
            else vfre[(fb + r) * 64 + d] = v;
          } else {
            const float s2 = v * v + __shfl_xor(v * v, 16);
            if (!isim) {
              if (mat == 0) sq_q[(fb + r) * 64 + d] = s2;
              else sq_k[(fb + r) * 64 + d] = s2;
            }
          }
        }
      }
    }
    __syncthreads();
    float nqs = 0.f, nks = 0.f;
#pragma unroll
    for (int w = 0; w < 4; ++w) { nqs += smem[12800 + w]; nks += smem[12808 + w]; }
    const float inv_nq = rsqrtf(nqs);
    const float inv_nk = rsqrtf(nks);
    for (int i = tid; i < 2048; i += 256)
      sq_k[i] = 0.25f * inv_nk * sqrtf(sq_k[i]);
    __syncthreads();
    {
      const int d = tid & 63, fb2 = tid >> 6, hd = d & 15;
      const float* wqa = ws + OFF_WQA;
      float wacc[32];
#pragma unroll
      for (int j = 0; j < 32; ++j) wacc[j] = 0.f;
      for (int r8 = 0; r8 < 8; ++r8) {
        const int m = fb2 + (r8 << 2);
        const float aq = inv_nq * sqrtf(sq_q[m * 64 + d]);
        float sv[32];
        float mx = -1e30f;
#pragma unroll
        for (int j = 0; j < 32; ++j) {
          const float a = (j == 0) ? aq : wqa[(m * 31 + (j - 1)) * 16 + hd];
          const float s = sq_k[j * 64 + d] * a;
          sv[j] = s;
          mx = fmaxf(mx, s);
        }
        float sum = 0.f;
#pragma unroll
        for (int j = 0; j < 32; ++j) {
          const float ev = __expf(sv[j] - mx);
          sv[j] = ev;
          sum += ev;
        }
        const float sc = 0.03125f / sum;
#pragma unroll
        for (int j = 0; j < 32; ++j) wacc[j] += sv[j] * sc;
      }
#pragma unroll
      for (int j = 0; j < 32; ++j) atomicAdd(&wbar[j * 64 + d], wacc[j]);
    }
    __syncthreads();
    unsigned int* OFTu = (unsigned int*)(ws + OFF_OFT) + (size_t)bt * 2048;
    for (int i2 = tid; i2 < 2048; i2 += 256) {
      const int d = i2 >> 5, j = i2 & 31;
      const float w = wbar[j * 64 + d];
      const unsigned int lo = f2bf(vfre[j * 64 + d] * w);
      const unsigned int hi = f2bf(vfim[j * 64 + d] * w);
      OFTu[i2] = lo | (hi << 16);
    }
  } else if (blk < 1359) {
    // ================= linear2 (Wc only): xc -> XCT =================
    const int blk2 = blk - 384;
    u16* XAu = (u16*)smem;                 // [128][72] u16; reused as xcT[64][132]
    const size_t base = (size_t)blk2 * 128;
    const u16* WBBu = (const u16*)(ws + OFF_WBB);

    for (int i = tid; i < 2048; i += 256) {
      const int row = i >> 4, e0 = (i & 15) * 4;
      const float4 v = *(const float4*)(x + (base + row) * 64 + e0);
      u16* dst = &XAu[row * 72 + e0];
      dst[0] = f2bf(v.x); dst[1] = f2bf(v.y); dst[2] = f2bf(v.z); dst[3] = f2bf(v.w);
    }
    __syncthreads();

    floatx4 acc[2][4] = {};
#pragma unroll
    for (int kc = 0; kc < 2; ++kc) {
      short8 af[2];
#pragma unroll
      for (int mi = 0; mi < 2; ++mi)
        af[mi] = *(const short8*)&XAu[(32 * wv + 16 * mi + lc) * 72 + kc * 32 + quad * 8];
#pragma unroll
      for (int ni = 0; ni < 4; ++ni) {
        const short8 bf_ = *(const short8*)&WBBu[(ni * 16 + lc) * 64 + kc * 32 + quad * 8];
#pragma unroll
        for (int mi = 0; mi < 2; ++mi)
          acc[mi][ni] = __builtin_amdgcn_mfma_f32_16x16x32_bf16(af[mi], bf_, acc[mi][ni], 0, 0, 0);
      }
    }
    __syncthreads();   // all XA reads complete before xcT overwrite

    u16* xcT = XAu;    // [64 d][132]
#pragma unroll
    for (int ni = 0; ni < 4; ++ni)
#pragma unroll
      for (int mi = 0; mi < 2; ++mi)
#pragma unroll
        for (int reg = 0; reg < 4; ++reg)
          xcT[(ni * 16 + lc) * 132 + 32 * wv + 16 * mi + quad * 4 + reg] =
              f2bf(acc[mi][ni][reg]);
    __syncthreads();
    u16* XCT = (u16*)(ws + OFF_XCT);
    for (int i = tid; i < 8192; i += 256) {
      const int d = i >> 7, r = i & 127;
      const unsigned int row = (unsigned int)(base + r);
      const unsigned int bt = row / 325u;
      const unsigned int n = row - bt * 325u;
      XCT[(size_t)bt * 22528 + (size_t)d * 352 + n] = xcT[d * 132 + r];
    }
  } else {
    // ================= xa: alternating sums of x =================
    const int idx = (blk - 1359) * 256 + tid;
    if (idx >= 32 * 325 * 16) return;
    const int dq = idx & 15;            // float4 slot
    const int n = (idx >> 4) % 325;
    const int b = idx / (16 * 325);
    const float* xp = x + ((size_t)b * 3900 + (size_t)n * 12) * 64 + dq * 4;
    float4 s = make_float4(0.f, 0.f, 0.f, 0.f);
    float sign = 1.f;
    for (int k = 0; k < 12; ++k) {
      const float4 v = *(const float4*)(xp + (size_t)k * 64);
      s.x += sign * v.x; s.y += sign * v.y; s.z += sign * v.z; s.w += sign * v.w;
      sign = -sign;
    }
    *(float4*)(ws + OFF_XA + ((size_t)b * 325 + n) * 64 + dq * 4) = s;
  }
}

// =======  K3: barrier-free MFMA — C = AN@XCT + T2@OFT + TE@Wvt + bias  =======
__global__ __launch_bounds__(256) void k_final2(const float* __restrict__ x,
                                                const float* __restrict__ bmlp,
                                                float* __restrict__ ws,
                                                float* __restrict__ out) {
  const int tid = threadIdx.x;
  const int bt = blockIdx.x / 3, mc = blockIdx.x % 3;
  const int m0 = mc * 128;
  const int wave = tid >> 6, lane = tid & 63;
  const int quad = lane >> 4, lc = lane & 15;

  const u16* ANB = (const u16*)(ws + OFF_ANB);
  const u16* T2B = (const u16*)(ws + OFF_T2);
  const u16* XCT = (const u16*)(ws + OFF_XCT) + (size_t)bt * 22528;
  const u16* OFT = (const u16*)(ws + OFF_OFT) + (size_t)bt * 4096;
  const u16* WVTBu = (const u16*)(ws + OFF_WVTB);

  const int b = bt / 12, t = bt - b * 12;
  const float sgn12 = ((t & 1) ? -1.f : 1.f) * (1.f / 12.f);

  floatx4 acc[2][4] = {};

#pragma unroll
  for (int c13 = 0; c13 < 13; ++c13) {
    const bool gcn = (c13 < 11);
    const u16* Asrc = gcn ? ANB : T2B;
    const int astr = gcn ? 352 : 64;
    const int acol = gcn ? c13 * 32 : (c13 - 11) * 32;
    const u16* Bsrc = gcn ? XCT : OFT;
    const int bstr = gcn ? 352 : 64;
    short8 af[2], bf_[4];
#pragma unroll
    for (int mi = 0; mi < 2; ++mi) {
      const int gr = m0 + wave * 32 + mi * 16 + lc;
      short8 a = {};
      if (gr < 325)
        a = *(const short8*)&Asrc[(size_t)gr * astr + acol + quad * 8];
      af[mi] = a;
    }
#pragma unroll
    for (int ni = 0; ni < 4; ++ni)
      bf_[ni] = *(const short8*)&Bsrc[(size_t)(ni * 16 + lc) * bstr + acol + quad * 8];
#pragma unroll
    for (int mi = 0; mi < 2; ++mi)
#pragma unroll
      for (int ni = 0; ni < 4; ++ni)
        acc[mi][ni] = __builtin_amdgcn_mfma_f32_16x16x32_bf16(
            af[mi], bf_[ni], acc[mi][ni], 0, 0, 0);
  }

  // --- te GEMM: A' = (x_row(n*12+t) - sgn*xa_n/12)/6, B = Wvt ---
#pragma unroll
  for (int kc = 0; kc < 2; ++kc) {
    const int k0 = kc * 32 + quad * 8;
    short8 af[2];
#pragma unroll
    for (int mi = 0; mi < 2; ++mi) {
      const int nr = m0 + wave * 32 + mi * 16 + lc;
      short8 a = {};
      if (nr < 325) {
        const float* xp = x + ((size_t)b * 3900 + (size_t)nr * 12 + t) * 64 + k0;
        const float* xap = ws + OFF_XA + ((size_t)b * 325 + nr) * 64 + k0;
        float xv[8], av[8];
        *(float4*)xv = *(const float4*)xp;
        *(float4*)(xv + 4) = *(const float4*)(xp + 4);
        *(float4*)av = *(const float4*)xap;
        *(float4*)(av + 4) = *(const float4*)(xap + 4);
#pragma unroll
        for (int u = 0; u < 8; ++u)
          a[u] = (short)f2bf((xv[u] - sgn12 * av[u]) * (1.f / 6.f));
      }
      af[mi] = a;
    }
#pragma unroll
    for (int ni = 0; ni < 4; ++ni) {
      const short8 bf_ = *(const short8*)&WVTBu[(size_t)(ni * 16 + lc) * 64 + k0];
#pragma unroll
      for (int mi = 0; mi < 2; ++mi)
        acc[mi][ni] = __builtin_amdgcn_mfma_f32_16x16x32_bf16(
            af[mi], bf_, acc[mi][ni], 0, 0, 0);
    }
  }

#pragma unroll
  for (int ni = 0; ni < 4; ++ni) {
    const int d = ni * 16 + lc;
    const float bias = bmlp[d];
#pragma unroll
    for (int mi = 0; mi < 2; ++mi) {
#pragma unroll
      for (int reg = 0; reg < 4; ++reg) {
        const int n = m0 + wave * 32 + mi * 16 + quad * 4 + reg;
        if (n >= 325) continue;
        out[((size_t)bt * 325 + n) * 64 + d] = acc[mi][ni][reg] + bias;
      }
    }
  }
}

extern "C" void kernel_launch(void* const* d_in, const int* in_sizes, int n_in,
                              void* d_out, int out_size, void* d_ws, size_t ws_size,
                              hipStream_t stream) {
  const float* x = (const float*)d_in[0];
  const float* adj = (const float*)d_in[1];
  const float* Wq_g = (const float*)d_in[2];
  const float* Wk_g = (const float*)d_in[3];
  const float* Wv_g = (const float*)d_in[4];
  // d_in[5], d_in[6] (Wq_t, Wk_t), d_in[12] (weights_Q_t), d_in[14] (t_modes):
  // dead code — temporal softmax axis == mean axis => out = vf/6.
  const float* Wv_t = (const float*)d_in[7];
  const float* Wfc1 = (const float*)d_in[8];
  const float* Wmlp = (const float*)d_in[9];
  const float* bmlp = (const float*)d_in[10];
  const float* wQ = (const float*)d_in[11];
  const int* sp_modes = (const int*)d_in[13];
  float* ws = (float*)d_ws;
  float* out = (float*)d_out;

  (void)in_sizes; (void)n_in; (void)out_size; (void)ws_size;

  k_prep<<<1439, 256, 0, stream>>>(x, adj, Wmlp, Wfc1, wQ, Wv_t, Wq_g, Wk_g, Wv_g,
                                   sp_modes, ws);
  k_mega<<<2009, 256, 0, stream>>>(x, ws);
  k_final2<<<1152, 256, 0, stream>>>(x, bmlp, ws, out);
}